// Round 14
// baseline (237.469 us; speedup 1.0000x reference)
//
#include <hip/hip_runtime.h>

// CrossAttention B=16, N1=N2=2048, D=512, L=256 — algebraic restructure +
// fused S~/U kernel, 2 key-halves, 48 KiB LDS (X2 32K | S 16K) for real
// 2-blocks/CU (round-13's 80K x2 = exactly 160K didn't fit -> 1 block/CU).
// PV's TX2 operand now loads global->registers (16B contiguous per fragment,
// 64B-coalesced across lanes, L2-resident) instead of LDS staging.
//   W' = Wk·Wq^T, bq' = bq·Wk^T; Q' = X1·W'^T + bq'
//   fused (16x16x2): S=exp(Q'X2^T/√512) in LDS, U_h = S·X2, Pt partials
//   out = Iv·(U·[WvT|WvT]^T) + bv   (K=512 contraction sums the halves)

#define DIMD 512
#define LENL 256
#define BATCH 16
#define NQ 2048
#define NKV 2048

using bf16x8 = __attribute__((ext_vector_type(8))) __bf16;
using f32x4  = __attribute__((ext_vector_type(4))) float;
typedef unsigned short u16;

__device__ __forceinline__ u16 f2bf(float f) {
  union { float f; unsigned u; } x; x.f = f;
  return (u16)((x.u + 0x7fffu + ((x.u >> 16) & 1u)) >> 16);
}
__device__ __forceinline__ float bf2f(u16 b) {
  union { unsigned u; float f; } x; x.u = ((unsigned)b) << 16;
  return x.f;
}

__global__ __launch_bounds__(256) void k_cvt(const float* __restrict__ src,
                                             u16* __restrict__ dst, int n4) {
  int i = blockIdx.x * blockDim.x + threadIdx.x;
  int stride = gridDim.x * blockDim.x;
  for (; i < n4; i += stride) {
    float4 v = ((const float4*)src)[i];
    ushort4 o;
    o.x = f2bf(v.x); o.y = f2bf(v.y); o.z = f2bf(v.z); o.w = f2bf(v.w);
    ((ushort4*)dst)[i] = o;
  }
}

// fused: in2 f32 [z][2048][256] -> A2 bf16 (same layout) + TX2 bf16 [z][256][2048]
__global__ __launch_bounds__(256) void k_cvt_t(const float* __restrict__ in2,
                                               u16* __restrict__ A2,
                                               u16* __restrict__ TX2) {
  __shared__ u16 t[32][33];
  int bx = blockIdx.x * 32;  // L (256)
  int by = blockIdx.y * 32;  // keys (2048)
  long z = blockIdx.z;
  const float* s = in2 + z * (2048L * 256);
  u16* a = A2 + z * (2048L * 256);
  u16* d = TX2 + z * (256L * 2048);
  int tx = threadIdx.x, ty = threadIdx.y;  // (32,8)
#pragma unroll
  for (int i = 0; i < 4; i++) {
    u16 v = f2bf(s[(size_t)(by + ty + 8 * i) * 256 + (bx + tx)]);
    a[(size_t)(by + ty + 8 * i) * 256 + (bx + tx)] = v;
    t[ty + 8 * i][tx] = v;
  }
  __syncthreads();
#pragma unroll
  for (int i = 0; i < 4; i++)
    d[(size_t)(bx + ty + 8 * i) * 2048 + (by + tx)] = t[tx][ty + 8 * i];
}

// Wv[256][512] f32 -> WvTk[512][512] bf16 with WvTk[n][k] = Wv[k%256][n]
__global__ __launch_bounds__(256) void k_transpose_dup(
    const float* __restrict__ Wv, u16* __restrict__ WvTk) {
  __shared__ float t[32][33];
  int bx = blockIdx.x * 32;  // n (512)
  int by = blockIdx.y * 32;  // k (256)
  int tx = threadIdx.x, ty = threadIdx.y;  // (32,8)
#pragma unroll
  for (int i = 0; i < 4; i++)
    t[ty + 8 * i][tx] = Wv[(size_t)(by + ty + 8 * i) * 512 + (bx + tx)];
  __syncthreads();
#pragma unroll
  for (int i = 0; i < 4; i++) {
    u16 v = f2bf(t[tx][ty + 8 * i]);
    WvTk[(size_t)(bx + ty + 8 * i) * 512 + (by + tx)] = v;
    WvTk[(size_t)(bx + ty + 8 * i) * 512 + 256 + (by + tx)] = v;
  }
}

__global__ __launch_bounds__(256) void k_bqp(const float* __restrict__ bq,
                                             const float* __restrict__ Wk,
                                             float* __restrict__ bqp) {
  int n = threadIdx.x;
  float s = 0.f;
  for (int o = 0; o < 512; o += 4) {
    float4 w = *(const float4*)&Wk[(size_t)n * 512 + o];
    float4 b = *(const float4*)&bq[o];
    s += w.x * b.x + w.y * b.y + w.z * b.z + w.w * b.w;
  }
  bqp[n] = s;
}

__device__ __forceinline__ void gl_lds16(const void* g, void* l) {
  __builtin_amdgcn_global_load_lds(
      (const __attribute__((address_space(1))) void*)g,
      (__attribute__((address_space(3))) void*)l, 16, 0, 0);
}

__device__ __forceinline__ void xcd_swz(int& bx, int& by, int& bz) {
  const int nx = gridDim.x, ny = gridDim.y, nz = gridDim.z;
  const long nwg = (long)nx * ny * nz;
  if (nwg & 7) return;
  long lin = (long)bx + (long)nx * ((long)by + (long)ny * bz);
  const long q = nwg >> 3;
  const long nl = (lin & 7) * q + (lin >> 3);
  bx = (int)(nl % nx);
  long r2 = nl / nx;
  by = (int)(r2 % ny);
  bz = (int)(r2 / ny);
}

#define MF(a, b, c) __builtin_amdgcn_mfma_f32_16x16x32_bf16(a, b, c, 0, 0, 0)

// ================== fused S~ / U kernel (48 KiB LDS, 2 blocks/CU) ============
// Block: 128 q-rows x 1024 keys (half h). 16 iters of 64 keys:
//  STG_X2(i)+LOAD_TF0 -> vmcnt(4) bar -> QK->S -> lgkm bar ->
//  LOAD_TF1 -> PV kk0 (tf0 regs) -> PV kk1 (tf1 regs) -> bar.
// LDS: X2 [0,32K) | S [32K,48K); part aliases S post-loop.
__global__ __launch_bounds__(512, 2) void k_fused_su(
    const u16* __restrict__ Qp, const u16* __restrict__ X2g,
    const u16* __restrict__ TXg, u16* __restrict__ U,
    float* __restrict__ Pt, float scale) {
  __shared__ __align__(16) char lds[49152];
  float* part = (float*)(lds + 32768);  // aliases S; post-loop only

  int bxi = blockIdx.x, byi = blockIdx.y, bzi = blockIdx.z;
  xcd_swz(bxi, byi, bzi);
  const int tid = threadIdx.x, lane = tid & 63, wid = tid >> 6;
  const int fr = lane & 15, kq = lane >> 4, fr7 = fr & 7;
  const int row0 = bxi * 128;
  const long z = byi;
  const int h = bzi;                      // key half
  const int kh = wid & 1, rq = wid >> 1;  // QK: 32 keys x 32 rows per wave
  const int wr = wid >> 2, wc = wid & 3;  // PV: 64 rows x 64 cols per wave

  // Q' fragments: rows rq*32 + ni*16 + fr, l-octet (kk*4+kq)*8
  bf16x8 qf[2][8];
  {
    const u16* qb = Qp + ((long)z * 2048 + row0 + rq * 32) * 256;
#pragma unroll
    for (int ni = 0; ni < 2; ni++)
#pragma unroll
      for (int kk = 0; kk < 8; kk++)
        qf[ni][kk] =
            *(const bf16x8*)(qb + (ni * 16 + fr) * 256 + kk * 32 + kq * 8);
  }

  const u16* gX2 = X2g + (long)z * (2048 * 256) + (long)h * 1024 * 256;
  const u16* gTX = TXg + (long)z * (256 * 2048) + (long)h * 1024;
  const int xrow = tid >> 5, xs = tid & 31;  // X2 tile: 64 rows x 512B
  // PV B-operand base: row wc*64 + n*16 + fr of TX2, key octet kq*8
  const u16* tb = gTX + (long)(wc * 64 + fr) * 2048 + kq * 8;

#define STG_X2(ii) { \
  _Pragma("unroll") for (int p = 0; p < 4; p++) { \
    const int r_ = p * 16 + xrow; \
    gl_lds16(gX2 + ((long)(ii) * 64 + r_) * 256 + (xs ^ (r_ & 7)) * 8, \
             lds + (p * 512 + tid) * 16); } }
// tf load: keys (kk*4+kq)*8 .. +7 of iter i (absolute key i*64 + ...)
#define LOAD_TF(kk, dst) { \
  _Pragma("unroll") for (int n = 0; n < 4; n++) \
    dst[n] = *(const bf16x8*)(tb + (long)n * 32768 + i * 64 + (kk) * 32); }

  f32x4 accU[4][4];
  const f32x4 zero = {0.f, 0.f, 0.f, 0.f};
#pragma unroll
  for (int m = 0; m < 4; m++)
#pragma unroll
    for (int n = 0; n < 4; n++) accU[m][n] = zero;
  float rs0 = 0.f, rs1 = 0.f;

  for (int i = 0; i < 16; i++) {
    bf16x8 tf0[4], tf1[4];
    STG_X2(i);
    LOAD_TF(0, tf0);
    asm volatile("s_waitcnt vmcnt(4)" ::: "memory");  // X2 staged (tf0 in flight)
    __builtin_amdgcn_sched_barrier(0);
    __builtin_amdgcn_s_barrier();
    __builtin_amdgcn_sched_barrier(0);

    // ---- QK -> S ----
    {
      f32x4 accS[2][2];
      accS[0][0] = zero; accS[0][1] = zero;
      accS[1][0] = zero; accS[1][1] = zero;
      __builtin_amdgcn_s_setprio(1);
#pragma unroll
      for (int kk = 0; kk < 8; kk++) {
        const int so = ((kk * 4 + kq) ^ fr7) << 4;
        bf16x8 xf0 = *(const bf16x8*)(lds + (kh * 32 + fr) * 512 + so);
        bf16x8 xf1 = *(const bf16x8*)(lds + (kh * 32 + 16 + fr) * 512 + so);
        accS[0][0] = MF(xf0, qf[0][kk], accS[0][0]);
        accS[0][1] = MF(xf0, qf[1][kk], accS[0][1]);
        accS[1][0] = MF(xf1, qf[0][kk], accS[1][0]);
        accS[1][1] = MF(xf1, qf[1][kk], accS[1][1]);
      }
      __builtin_amdgcn_s_setprio(0);
#pragma unroll
      for (int mi = 0; mi < 2; mi++)
#pragma unroll
        for (int ni = 0; ni < 2; ni++) {
          u16 e[4];
          float sum4 = 0.f;
#pragma unroll
          for (int r = 0; r < 4; r++) {
            float v = accS[mi][ni][r] * scale;
            float ef = __expf(fminf(v, 30.f));
            e[r] = f2bf(ef);
            sum4 += bf2f(e[r]);
          }
          if (ni == 0) rs0 += sum4; else rs1 += sum4;
          unsigned long long w =
              (unsigned long long)((unsigned)e[0] | ((unsigned)e[1] << 16)) |
              ((unsigned long long)((unsigned)e[2] | ((unsigned)e[3] << 16)) << 32);
          const int row = rq * 32 + ni * 16 + fr;
          const int inrow = (kh * 64 + mi * 32 + kq * 8) ^ (fr7 << 4);
          *(unsigned long long*)(lds + 32768 + row * 128 + inrow) = w;
        }
    }
    asm volatile("s_waitcnt lgkmcnt(0)" ::: "memory");
    __builtin_amdgcn_sched_barrier(0);
    __builtin_amdgcn_s_barrier();
    __builtin_amdgcn_sched_barrier(0);

    // ---- PV: accU += S · TX2(regs) ----
    LOAD_TF(1, tf1);
    __builtin_amdgcn_s_setprio(1);
    {
      const int so0 = (kq ^ fr7) << 4;  // kk=0
      bf16x8 sf[4];
#pragma unroll
      for (int m = 0; m < 4; m++)
        sf[m] = *(const bf16x8*)(lds + 32768 + (wr * 64 + m * 16 + fr) * 128 + so0);
#pragma unroll
      for (int m = 0; m < 4; m++)
#pragma unroll
        for (int n = 0; n < 4; n++)
          accU[m][n] = MF(sf[m], tf0[n], accU[m][n]);
      const int so1 = ((4 + kq) ^ fr7) << 4;  // kk=1
#pragma unroll
      for (int m = 0; m < 4; m++)
        sf[m] = *(const bf16x8*)(lds + 32768 + (wr * 64 + m * 16 + fr) * 128 + so1);
#pragma unroll
      for (int m = 0; m < 4; m++)
#pragma unroll
        for (int n = 0; n < 4; n++)
          accU[m][n] = MF(sf[m], tf1[n], accU[m][n]);
    }
    __builtin_amdgcn_s_setprio(0);
    __builtin_amdgcn_sched_barrier(0);
    __builtin_amdgcn_s_barrier();   // S/X2 reads consumed; safe to restage
    __builtin_amdgcn_sched_barrier(0);
  }
#undef STG_X2
#undef LOAD_TF

  // rowsum partials -> Pt[h][z][row]  (part aliases S; S dead)
  __syncthreads();
  if (tid < 128) part[tid] = 0.f;
  __syncthreads();
  {
    float s0 = rs0, s1 = rs1;
    s0 += __shfl_xor(s0, 16); s0 += __shfl_xor(s0, 32);
    s1 += __shfl_xor(s1, 16); s1 += __shfl_xor(s1, 32);
    if (lane < 16) {
      atomicAdd(&part[rq * 32 + lane], s0);
      atomicAdd(&part[rq * 32 + 16 + lane], s1);
    }
  }
  __syncthreads();
  if (tid < 128) Pt[((long)h * 16 + z) * 2048 + row0 + tid] = part[tid];

  // U store: half h -> cols [h*256, h*256+256) of U[32768][512]
  u16* ub = U + ((long)z * 2048 + row0) * 512 + h * 256;
#pragma unroll
  for (int m = 0; m < 4; m++)
#pragma unroll
    for (int n = 0; n < 4; n++) {
      const int col = wc * 64 + n * 16 + fr;
#pragma unroll
      for (int r = 0; r < 4; r++) {
        const int row = wr * 64 + m * 16 + kq * 4 + r;
        ub[row * 512 + col] = f2bf(accU[m][n][r]);
      }
    }
}

// ---------- Iv[i] = 1 / (Pt[0][i] + Pt[1][i]) ----------
__global__ __launch_bounds__(256) void k_invsum(const float* __restrict__ Pt,
                                                float* __restrict__ inv) {
  int i = blockIdx.x * blockDim.x + threadIdx.x;  // 0..32767
  inv[i] = 1.f / (Pt[i] + Pt[32768 + i]);
}

// =============== 256-row 8-wave gemm_bt (round-7 proven form) =================
#define SA(p, h, l, T) \
  gl_lds16(gA + (long)((h) * 128 + (l) * 64) * lda + (T) * 64, \
           dA + (p) * 32768 + (h) * 16384 + (l) * 8192)
#define SB(p, h, l, T) \
  gl_lds16(gB + (long)((h) * 128 + (l) * 64) * ldb + (T) * 64, \
           dB + (p) * (BNH * 16384) + (h) * 16384 + (l) * 8192)
#define RD_A(p, mh) { _Pragma("unroll") for (int m = 0; m < 4; m++) { \
    afr[m][0] = *(const bf16x8*)(lds + (p) * 32768 + aoffb + ((mh) * 64 + m * 16) * 128 + sb0); \
    afr[m][1] = *(const bf16x8*)(lds + (p) * 32768 + aoffb + ((mh) * 64 + m * 16) * 128 + sb1); } }
#define RD_B(p, nh, BF) { _Pragma("unroll") for (int n = 0; n < 2; n++) { \
    BF[n][0] = *(const bf16x8*)(lds + (p) * (BNH * 16384) + boffb + (((nh) * 2 + n) * 16) * 128 + sb0); \
    BF[n][1] = *(const bf16x8*)(lds + (p) * (BNH * 16384) + boffb + (((nh) * 2 + n) * 16) * 128 + sb1); } }
#define MFMA_QUAD(mh, nh, BF) { \
  _Pragma("unroll") for (int m = 0; m < 4; m++) \
  _Pragma("unroll") for (int n = 0; n < 2; n++) \
  _Pragma("unroll") for (int kk = 0; kk < 2; kk++) \
    acc[(mh) * 4 + m][(nh) * 2 + n] = MF(afr[m][kk], BF[n][kk], \
                                         acc[(mh) * 4 + m][(nh) * 2 + n]); }
#define BAR_MFMA_OPEN() \
  __builtin_amdgcn_sched_barrier(0); \
  __builtin_amdgcn_s_barrier(); \
  asm volatile("s_waitcnt lgkmcnt(0)" ::: "memory"); \
  __builtin_amdgcn_sched_barrier(0); \
  __builtin_amdgcn_s_setprio(1)
#define PH_CLOSE() \
  __builtin_amdgcn_s_setprio(0); \
  __builtin_amdgcn_sched_barrier(0); \
  __builtin_amdgcn_s_barrier(); \
  __builtin_amdgcn_sched_barrier(0)
#define PH_CLOSE_VM(N) \
  __builtin_amdgcn_s_setprio(0); \
  asm volatile("s_waitcnt vmcnt(" #N ")" ::: "memory"); \
  __builtin_amdgcn_sched_barrier(0); \
  __builtin_amdgcn_s_barrier(); \
  __builtin_amdgcn_sched_barrier(0)

template <int BNH, int OUT_BF16, int BIAS_MODE, int FUSE>
__global__ __launch_bounds__(512, 2) void k_gemm256(
    const u16* __restrict__ A, const u16* __restrict__ BT,
    void* __restrict__ Cv, const float* __restrict__ bias,
    const float* __restrict__ finv,
    int K, int lda, int ldb, int ldc, long sA, long sB, long sC, float scale) {
  __shared__ __align__(16) char lds[65536 + BNH * 32768 + 1024];
  float* part = (float*)(lds + 65536 + BNH * 32768);

  int bxi = blockIdx.x, byi = blockIdx.y, bzi = blockIdx.z;
  xcd_swz(bxi, byi, bzi);
  const int tid = threadIdx.x, lane = tid & 63, wid = tid >> 6;
  const int wr = wid >> 2, wc = wid & 3;
  const int fr = lane & 15, kq = lane >> 4, fr7 = fr & 7;
  const int brow = byi * 256, bcol = bxi * (BNH * 128);
  const long z = bzi;

  if (FUSE == 3 && tid < 256) part[tid] = finv[z * 2048 + brow + tid];

  const int srow = tid >> 3;
  const int sslot = (tid & 7) ^ (srow & 7);
  const u16* gA = A + z * sA + (long)(brow + srow) * lda + sslot * 8;
  const u16* gB = BT + z * sB + (long)(bcol + srow) * ldb + sslot * 8;
  char* dA = lds + tid * 16;
  char* dB = lds + 65536 + tid * 16;

  const int aoffb = (wr * 128 + fr) * 128;
  const int boffb = 65536 + (wc * (BNH * 32) + fr) * 128;
  const int sb0 = (kq ^ fr7) * 16;
  const int sb1 = ((4 + kq) ^ fr7) * 16;

  f32x4 acc[8][2 * BNH];
  const f32x4 zero = {0.f, 0.f, 0.f, 0.f};
#pragma unroll
  for (int m = 0; m < 8; m++)
#pragma unroll
    for (int n = 0; n < 2 * BNH; n++) acc[m][n] = zero;

  bf16x8 afr[4][2], bf0[2][2], bf1[2][2];
  const int iters = K >> 7;

  if (BNH == 2) {
    SA(0, 0, 0, 0); SA(0, 0, 1, 0); SA(0, 1, 0, 0); SA(0, 1, 1, 0);
    SB(0, 0, 0, 0); SB(0, 0, 1, 0); SB(0, 1, 0, 0); SB(0, 1, 1, 0);
    SB(1, 0, 0, 1); SB(1, 0, 1, 1); SB(1, 1, 0, 1); SB(1, 1, 1, 1);
    asm volatile("s_waitcnt vmcnt(4)" ::: "memory");
    __builtin_amdgcn_sched_barrier(0);
    __builtin_amdgcn_s_barrier();
    for (int i = 0; i < iters; i++) {
      const int t1 = 2 * i + 1, p0 = 2 * i + 2, p1 = 2 * i + 3;
      const bool more = (i + 1 < iters);
      RD_A(0, 0); RD_B(0, 0, bf0);
      SA(1, 0, 0, t1); SA(1, 0, 1, t1);
      BAR_MFMA_OPEN(); MFMA_QUAD(0, 0, bf0); PH_CLOSE();
      RD_B(0, 1, bf1);
      SA(1, 1, 0, t1); SA(1, 1, 1, t1);
      BAR_MFMA_OPEN(); MFMA_QUAD(0, 1, bf1); PH_CLOSE();
      RD_A(0, 1);
      if (more) { SB(0, 0, 0, p0); SB(0, 0, 1, p0); }
      BAR_MFMA_OPEN(); MFMA_QUAD(1, 0, bf0); PH_CLOSE();
      if (more) { SB(0, 1, 0, p0); SB(0, 1, 1, p0); }
      BAR_MFMA_OPEN(); MFMA_QUAD(1, 1, bf1);
      if (more) { PH_CLOSE_VM(4); } else { PH_CLOSE_VM(0); }
      RD_A(1, 0); RD_B(1, 0, bf0);
      if (more) { SA(0, 0, 0, p0); SA(0, 0, 1, p0); }
      BAR_MFMA_OPEN(); MFMA_QUAD(0, 0, bf0); PH_CLOSE();
      RD_B(1, 1, bf1);
      if (more) { SA(0, 1, 0, p0); SA(0, 1, 1, p0); }
      BAR_MFMA_OPEN(); MFMA_QUAD(0, 1, bf1); PH_CLOSE();
      RD_A(1, 1);
      if (more) { SB(1, 0, 0, p1); SB(1, 0, 1, p1); }
      BAR_MFMA_OPEN(); MFMA_QUAD(1, 0, bf0); PH_CLOSE();
      if (more) { SB(1, 1, 0, p1); SB(1, 1, 1, p1); }
      BAR_MFMA_OPEN(); MFMA_QUAD(1, 1, bf1);
      if (more) { PH_CLOSE_VM(4); } else { PH_CLOSE_VM(0); }
    }
  } else {
    SA(0, 0, 0, 0); SA(0, 0, 1, 0); SA(0, 1, 0, 0); SA(0, 1, 1, 0);
    SB(0, 0, 0, 0); SB(0, 0, 1, 0);
    SB(1, 0, 0, 1); SB(1, 0, 1, 1);
    asm volatile("s_waitcnt vmcnt(2)" ::: "memory");
    __builtin_amdgcn_sched_barrier(0);
    __builtin_amdgcn_s_barrier();
    for (int i = 0; i < iters; i++) {
      const int t1 = 2 * i + 1, p0 = 2 * i + 2, p1 = 2 * i + 3;
      const bool more = (i + 1 < iters);
      RD_A(0, 0); RD_B(0, 0, bf0);
      SA(1, 0, 0, t1); SA(1, 0, 1, t1);
      BAR_MFMA_OPEN(); MFMA_QUAD(0, 0, bf0); PH_CLOSE();
      RD_A(0, 1);
      SA(1, 1, 0, t1); SA(1, 1, 1, t1);
      if (more) { SB(0, 0, 0, p0); SB(0, 0, 1, p0); }
      BAR_MFMA_OPEN(); MFMA_QUAD(1, 0, bf0);
      if (more) { PH_CLOSE_VM(2); } else { PH_CLOSE_VM(0); }
      RD_A(1, 0); RD_B(1, 0, bf1);
      if (more) { SA(0, 0, 0, p0); SA(0, 0, 1, p0); }
      BAR_MFMA_OPEN(); MFMA_QUAD(0, 0, bf1); PH_CLOSE();
      RD_A(1, 1);
      if (more) { SA(0, 1, 0, p0); SA(0, 1, 1, p0);
                  SB(1, 0, 0, p1); SB(1, 0, 1, p1); }
      BAR_MFMA_OPEN(); MFMA_QUAD(1, 0, bf1);
      if (more) { PH_CLOSE_VM(2); } else { PH_CLOSE_VM(0); }
    }
  }

  const long zC = z * sC;
#pragma unroll
  for (int mi = 0; mi < 8; mi++) {
    const int r0 = brow + wr * 128 + mi * 16 + kq * 4;
#pragma unroll
    for (int n = 0; n < 2 * BNH; n++) {
      const int c = bcol + wc * (BNH * 32) + n * 16 + fr;
#pragma unroll
      for (int r = 0; r < 4; r++) {
        float v = acc[mi][n][r] * scale;
        if (BIAS_MODE == 1) v += bias[c];
        if (BIAS_MODE == 2) v += bias[r0 + r];
        if (FUSE == 3) v = v * part[r0 + r - brow] + bias[c];
        const long off = zC + (long)(r0 + r) * ldc + c;
        if (OUT_BF16) ((u16*)Cv)[off] = f2bf(v);
        else          ((float*)Cv)[off] = v;
      }
    }
  }
}

extern "C" void kernel_launch(void* const* d_in, const int* in_sizes, int n_in,
                              void* d_out, int out_size, void* d_ws, size_t ws_size,
                              hipStream_t stream) {
  (void)in_sizes; (void)n_in; (void)out_size;
  const float* in1 = (const float*)d_in[0];
  const float* in2 = (const float*)d_in[1];
  const float* Wq  = (const float*)d_in[2];
  const float* bq  = (const float*)d_in[3];
  const float* Wk  = (const float*)d_in[4];
  const float* Wv  = (const float*)d_in[6];
  const float* bv  = (const float*)d_in[7];
  float* out = (float*)d_out;

  const size_t MB = 1024ull * 1024ull;
  if (ws_size < 120 * MB) return;  // need ~115 MiB (proven ws >= 225 MiB)

  char* ws = (char*)d_ws;
  u16* A1   = (u16*)(ws + 0);                  // [32768][512] bf16 X1
  u16* A2   = (u16*)(ws + 32 * MB);            // [32768][256] bf16 X2
  u16* Qp   = (u16*)(ws + 48 * MB);            // [32768][256] Q'
  u16* TX2  = (u16*)(ws + 64 * MB);            // [16][256][2048] X2^T
  u16* U    = (u16*)(ws + 80 * MB);            // [32768][512] U halves
  u16* Wqb  = (u16*)(ws + 112 * MB);           // [512][512]
  u16* Wkb  = (u16*)(ws + 112 * MB + 524288);  // [256][512]
  u16* WT1  = (u16*)(ws + 112 * MB + 786432);  // [256][512] Wk·Wq^T
  u16* WvTk = (u16*)(ws + 113 * MB);           // [512][512] [WvT|WvT]
  float* bqp = (float*)(ws + 113 * MB + 524288);  // [256]
  float* Pt  = (float*)(ws + 114 * MB);           // [2][16][2048] partials
  float* Iv  = (float*)(ws + 114 * MB + 262144);  // [32768] inv row sums

  k_cvt<<<2048, 256, 0, stream>>>(in1, A1, 32768 * 512 / 4);
  k_cvt<<<256, 256, 0, stream>>>(Wq, Wqb, 512 * 512 / 4);
  k_cvt<<<128, 256, 0, stream>>>(Wk, Wkb, 256 * 512 / 4);
  k_cvt_t<<<dim3(8, 64, 16), dim3(32, 8), 0, stream>>>(in2, A2, TX2);
  k_transpose_dup<<<dim3(16, 8), dim3(32, 8), 0, stream>>>(Wv, WvTk);
  // W' = Wk·Wq^T ; bq' = bq·Wk^T
  k_gemm256<2, 1, 0, 0><<<dim3(2, 1, 1), 512, 0, stream>>>(
      Wkb, Wqb, WT1, nullptr, nullptr, 512, 512, 512, 512, 0, 0, 0, 1.f);
  k_bqp<<<1, 256, 0, stream>>>(bq, Wk, bqp);
  // Q' = X1·W'^T + bq'
  k_gemm256<1, 1, 1, 0><<<dim3(2, 128, 1), 512, 0, stream>>>(
      A1, WT1, Qp, bqp, nullptr, 512, 512, 512, 256, 0, 0, 0, 1.f);
  // fused: S~ per key-half; U halves; rowsum partials
  const float qk_scale = 0.044194173824159216f;
  k_fused_su<<<dim3(16, 16, 2), 512, 0, stream>>>(Qp, A2, TX2, U, Pt, qk_scale);
  k_invsum<<<128, 256, 0, stream>>>(Pt, Iv);
  // out = Iv·(U·[WvT|WvT]^T) + bv   (K=512 sums the two halves)
  k_gemm256<2, 0, 0, 3><<<dim3(2, 128, 1), 512, 0, stream>>>(
      U, WvTk, out, bv, Iv, 512, 512, 512, 512, 0, 0, 0, 1.f);
}

// Round 15
// 186.305 us; speedup vs baseline: 1.2746x; 1.2746x over previous
//
#include <hip/hip_runtime.h>

// CrossAttention B=16, N1=N2=2048, D=512, L=256 — algebraic restructure +
// fused S~/U kernel, software-pipelined: QK(i) || PV(i-1) per barrier pair,
// counted vmcnt(8), S double-buffered. 64-key geometry (128B/512B rows,
// fr&7 swizzles). [Round 15 = verified-best round-11 state restored after
// the 2-blocks/CU occupancy hypothesis failed three ways: (512,4) spilled,
// 80K didn't co-fit, and 48K+104VGPR still showed 1 block/CU while global
// tf loads added unhidden latency.]
//   W' = Wk·Wq^T, bq' = bq·Wk^T; Q' = X1·W'^T + bq'
//   fused: S = exp(Q'·X2^T/sqrt(512)) (LDS only), U = S·X2, Iv = 1/rowsum
//   out = Iv·(U·Wv) + bv

#define DIMD 512
#define LENL 256
#define BATCH 16
#define NQ 2048
#define NKV 2048

using bf16x8 = __attribute__((ext_vector_type(8))) __bf16;
using f32x4  = __attribute__((ext_vector_type(4))) float;
typedef unsigned short u16;

__device__ __forceinline__ u16 f2bf(float f) {
  union { float f; unsigned u; } x; x.f = f;
  return (u16)((x.u + 0x7fffu + ((x.u >> 16) & 1u)) >> 16);
}
__device__ __forceinline__ float bf2f(u16 b) {
  union { unsigned u; float f; } x; x.u = ((unsigned)b) << 16;
  return x.f;
}

__global__ __launch_bounds__(256) void k_cvt(const float* __restrict__ src,
                                             u16* __restrict__ dst, int n4) {
  int i = blockIdx.x * blockDim.x + threadIdx.x;
  int stride = gridDim.x * blockDim.x;
  for (; i < n4; i += stride) {
    float4 v = ((const float4*)src)[i];
    ushort4 o;
    o.x = f2bf(v.x); o.y = f2bf(v.y); o.z = f2bf(v.z); o.w = f2bf(v.w);
    ((ushort4*)dst)[i] = o;
  }
}

__global__ __launch_bounds__(256) void k_transpose(const float* __restrict__ W,
                                                   u16* __restrict__ WT,
                                                   int K, int N) {
  __shared__ float t[32][33];
  int bx = blockIdx.x * 32;
  int by = blockIdx.y * 32;
  int tx = threadIdx.x, ty = threadIdx.y;  // (32,8)
#pragma unroll
  for (int i = 0; i < 4; i++)
    t[ty + 8 * i][tx] = W[(size_t)(by + ty + 8 * i) * N + (bx + tx)];
  __syncthreads();
#pragma unroll
  for (int i = 0; i < 4; i++)
    WT[(size_t)(bx + ty + 8 * i) * K + (by + tx)] = f2bf(t[tx][ty + 8 * i]);
}

// fused: in2 f32 [z][2048][256] -> A2 bf16 (same layout) + TX2 bf16 [z][256][2048]
__global__ __launch_bounds__(256) void k_cvt_t(const float* __restrict__ in2,
                                               u16* __restrict__ A2,
                                               u16* __restrict__ TX2) {
  __shared__ u16 t[32][33];
  int bx = blockIdx.x * 32;  // L (256)
  int by = blockIdx.y * 32;  // keys (2048)
  long z = blockIdx.z;
  const float* s = in2 + z * (2048L * 256);
  u16* a = A2 + z * (2048L * 256);
  u16* d = TX2 + z * (256L * 2048);
  int tx = threadIdx.x, ty = threadIdx.y;  // (32,8)
#pragma unroll
  for (int i = 0; i < 4; i++) {
    u16 v = f2bf(s[(size_t)(by + ty + 8 * i) * 256 + (bx + tx)]);
    a[(size_t)(by + ty + 8 * i) * 256 + (bx + tx)] = v;
    t[ty + 8 * i][tx] = v;
  }
  __syncthreads();
#pragma unroll
  for (int i = 0; i < 4; i++)
    d[(size_t)(bx + ty + 8 * i) * 2048 + (by + tx)] = t[tx][ty + 8 * i];
}

__global__ __launch_bounds__(256) void k_bqp(const float* __restrict__ bq,
                                             const float* __restrict__ Wk,
                                             float* __restrict__ bqp) {
  int n = threadIdx.x;
  float s = 0.f;
  for (int o = 0; o < 512; o += 4) {
    float4 w = *(const float4*)&Wk[(size_t)n * 512 + o];
    float4 b = *(const float4*)&bq[o];
    s += w.x * b.x + w.y * b.y + w.z * b.z + w.w * b.w;
  }
  bqp[n] = s;
}

__device__ __forceinline__ void gl_lds16(const void* g, void* l) {
  __builtin_amdgcn_global_load_lds(
      (const __attribute__((address_space(1))) void*)g,
      (__attribute__((address_space(3))) void*)l, 16, 0, 0);
}

__device__ __forceinline__ void xcd_swz(int& bx, int& by, int& bz) {
  const int nx = gridDim.x, ny = gridDim.y, nz = gridDim.z;
  const long nwg = (long)nx * ny * nz;
  if (nwg & 7) return;
  long lin = (long)bx + (long)nx * ((long)by + (long)ny * bz);
  const long q = nwg >> 3;
  const long nl = (lin & 7) * q + (lin >> 3);
  bx = (int)(nl % nx);
  long r2 = nl / nx;
  by = (int)(r2 % ny);
  bz = (int)(r2 / ny);
}

#define MF(a, b, c) __builtin_amdgcn_mfma_f32_16x16x32_bf16(a, b, c, 0, 0, 0)

// ================== fused S~ / U kernel (QK || PV pipeline) ==================
// LDS: X2 dbuf 2x32K [0,64K) | TX2 dbuf 2x32K [64K,128K) | S dbuf 2x16K
// [128K,160K). part aliases S[0] (post-loop only). 160 KiB total, 1 block/CU.
// Per iter: stage X2(i+1)+TX2(i); vmcnt(8); barrier; QK(i)->S[i&1] and
// PV(i-1)<-S[(i-1)&1],TX2[(i-1)&1]; lgkmcnt(0); barrier.
__global__ __launch_bounds__(512, 2) void k_fused_su(
    const u16* __restrict__ Qp, const u16* __restrict__ X2g,
    const u16* __restrict__ TXg, u16* __restrict__ U,
    float* __restrict__ Iv, float scale) {
  __shared__ __align__(16) char lds[163840];
  float* part = (float*)(lds + 131072);  // aliases S[0]; used only post-loop

  int bxi = blockIdx.x, byi = blockIdx.y, bzi = blockIdx.z;
  xcd_swz(bxi, byi, bzi);
  const int tid = threadIdx.x, lane = tid & 63, wid = tid >> 6;
  const int fr = lane & 15, kq = lane >> 4, fr7 = fr & 7;
  const int row0 = bxi * 128;
  const long z = byi;
  const int kh = wid & 1, rq = wid >> 1;  // QK: 32 keys x 32 rows per wave
  const int wr = wid >> 2, wc = wid & 3;  // PV: 64 rows x 64 cols per wave

  // Q' fragments: rows rq*32 + ni*16 + fr, l-octet (kk*4+kq)*8
  bf16x8 qf[2][8];
  {
    const u16* qb = Qp + ((long)z * 2048 + row0 + rq * 32) * 256;
#pragma unroll
    for (int ni = 0; ni < 2; ni++)
#pragma unroll
      for (int kk = 0; kk < 8; kk++)
        qf[ni][kk] =
            *(const bf16x8*)(qb + (ni * 16 + fr) * 256 + kk * 32 + kq * 8);
  }

  const u16* gX2 = X2g + (long)z * (2048 * 256);
  const u16* gTX = TXg + (long)z * (256 * 2048);
  const int xrow = tid >> 5, xs = tid & 31;  // X2 tile: 64 rows x 512B
  const int trow = tid >> 3, ts = tid & 7;   // TX2 tile: 256 rows x 128B

#define STG_X2(ii, b) { \
  _Pragma("unroll") for (int p = 0; p < 4; p++) { \
    const int r_ = p * 16 + xrow; \
    gl_lds16(gX2 + ((long)(ii) * 64 + r_) * 256 + (xs ^ (r_ & 7)) * 8, \
             lds + (b) * 32768 + (p * 512 + tid) * 16); } }
#define STG_TX(ii, b) { \
  _Pragma("unroll") for (int p = 0; p < 4; p++) { \
    const int r_ = p * 64 + trow; \
    gl_lds16(gTX + (long)r_ * 2048 + (ii) * 64 + (ts ^ (r_ & 7)) * 8, \
             lds + 65536 + (b) * 32768 + (p * 512 + tid) * 16); } }

// QK(i): X2[xb] -> S[sb] (+ rowsum into rs0/rs1)
#define QK_BODY(xbuf, sbuf) { \
  f32x4 accS[2][2]; \
  accS[0][0] = zero; accS[0][1] = zero; accS[1][0] = zero; accS[1][1] = zero; \
  const char* xb = lds + (xbuf) * 32768; \
  _Pragma("unroll") for (int kk = 0; kk < 8; kk++) { \
    const int so = ((kk * 4 + kq) ^ fr7) << 4; \
    bf16x8 xf0 = *(const bf16x8*)(xb + (kh * 32 + fr) * 512 + so); \
    bf16x8 xf1 = *(const bf16x8*)(xb + (kh * 32 + 16 + fr) * 512 + so); \
    accS[0][0] = MF(xf0, qf[0][kk], accS[0][0]); \
    accS[0][1] = MF(xf0, qf[1][kk], accS[0][1]); \
    accS[1][0] = MF(xf1, qf[0][kk], accS[1][0]); \
    accS[1][1] = MF(xf1, qf[1][kk], accS[1][1]); \
  } \
  _Pragma("unroll") for (int mi = 0; mi < 2; mi++) \
  _Pragma("unroll") for (int ni = 0; ni < 2; ni++) { \
    u16 e[4]; float sum4 = 0.f; \
    _Pragma("unroll") for (int r = 0; r < 4; r++) { \
      float v = accS[mi][ni][r] * scale; \
      float ef = __expf(fminf(v, 30.f)); \
      e[r] = f2bf(ef); sum4 += bf2f(e[r]); \
    } \
    if (ni == 0) rs0 += sum4; else rs1 += sum4; \
    unsigned long long w = \
        (unsigned long long)((unsigned)e[0] | ((unsigned)e[1] << 16)) | \
        ((unsigned long long)((unsigned)e[2] | ((unsigned)e[3] << 16)) << 32); \
    const int row = rq * 32 + ni * 16 + fr; \
    const int inrow = (kh * 64 + mi * 32 + kq * 8) ^ (fr7 << 4); \
    *(unsigned long long*)(lds + 131072 + (sbuf) * 16384 + row * 128 + inrow) = w; \
  } }

// PV(i-1): S[sb] x TX2[tb] -> accU
#define PV_BODY(tbuf, sbuf) { \
  const char* tb = lds + 65536 + (tbuf) * 32768; \
  const char* sbase = lds + 131072 + (sbuf) * 16384; \
  _Pragma("unroll") for (int kk = 0; kk < 2; kk++) { \
    const int so = ((kk * 4 + kq) ^ fr7) << 4; \
    bf16x8 sf[4], tf[4]; \
    _Pragma("unroll") for (int m = 0; m < 4; m++) \
      sf[m] = *(const bf16x8*)(sbase + (wr * 64 + m * 16 + fr) * 128 + so); \
    _Pragma("unroll") for (int n = 0; n < 4; n++) \
      tf[n] = *(const bf16x8*)(tb + (wc * 64 + n * 16 + fr) * 128 + so); \
    _Pragma("unroll") for (int m = 0; m < 4; m++) \
    _Pragma("unroll") for (int n = 0; n < 4; n++) \
      accU[m][n] = MF(sf[m], tf[n], accU[m][n]); \
  } }

  f32x4 accU[4][4];
  const f32x4 zero = {0.f, 0.f, 0.f, 0.f};
#pragma unroll
  for (int m = 0; m < 4; m++)
#pragma unroll
    for (int n = 0; n < 4; n++) accU[m][n] = zero;
  float rs0 = 0.f, rs1 = 0.f;

  // prologue: X2(0), X2(1), TX2(0) = 12 ops in flight
  STG_X2(0, 0); STG_X2(1, 1); STG_TX(0, 0);
  asm volatile("s_waitcnt vmcnt(8)" ::: "memory");  // X2(0) landed
  __builtin_amdgcn_sched_barrier(0);
  __builtin_amdgcn_s_barrier();
  // peeled QK(0)
  __builtin_amdgcn_s_setprio(1);
  QK_BODY(0, 0);
  __builtin_amdgcn_s_setprio(0);
  asm volatile("s_waitcnt lgkmcnt(0)" ::: "memory");
  __builtin_amdgcn_sched_barrier(0);
  __builtin_amdgcn_s_barrier();
  __builtin_amdgcn_sched_barrier(0);

  for (int i = 1; i < 32; i++) {
    const int cur = i & 1, prv = cur ^ 1;
    const int pre = (i + 1 > 31) ? 31 : i + 1;  // dup-stage keeps count uniform
    STG_X2(pre, (i + 1) & 1);                   // dup target is a dead buffer
    STG_TX(i, cur);
    asm volatile("s_waitcnt vmcnt(8)" ::: "memory");  // X2(i), TX2(i-1) landed
    __builtin_amdgcn_sched_barrier(0);
    __builtin_amdgcn_s_barrier();
    __builtin_amdgcn_sched_barrier(0);
    __builtin_amdgcn_s_setprio(1);
    QK_BODY(cur, cur);   // independent of PV below: compiler interleaves
    PV_BODY(prv, prv);
    __builtin_amdgcn_s_setprio(0);
    asm volatile("s_waitcnt lgkmcnt(0)" ::: "memory");
    __builtin_amdgcn_sched_barrier(0);
    __builtin_amdgcn_s_barrier();
    __builtin_amdgcn_sched_barrier(0);
  }

  // epilogue: PV(31) (S[1], TX2[1]); TX2(31) needs full drain (it is newest)
  asm volatile("s_waitcnt vmcnt(0)" ::: "memory");
  __builtin_amdgcn_sched_barrier(0);
  __builtin_amdgcn_s_barrier();
  __builtin_amdgcn_s_setprio(1);
  PV_BODY(1, 1);
  __builtin_amdgcn_s_setprio(0);

#undef STG_X2
#undef STG_TX
#undef QK_BODY
#undef PV_BODY

  // rowsums -> Iv (part aliases S[0]; S is dead now)
  __syncthreads();
  if (tid < 128) part[tid] = 0.f;
  __syncthreads();
  {
    float s0 = rs0, s1 = rs1;
    s0 += __shfl_xor(s0, 16); s0 += __shfl_xor(s0, 32);
    s1 += __shfl_xor(s1, 16); s1 += __shfl_xor(s1, 32);
    if (lane < 16) {
      atomicAdd(&part[rq * 32 + lane], s0);
      atomicAdd(&part[rq * 32 + 16 + lane], s1);
    }
  }
  __syncthreads();
  if (tid < 128) Iv[z * 2048 + row0 + tid] = 1.f / part[tid];

  // U store (unnormalized bf16; out-GEMM applies Iv)
  u16* ub = U + ((long)z * 2048 + row0) * 256;
#pragma unroll
  for (int m = 0; m < 4; m++)
#pragma unroll
    for (int n = 0; n < 4; n++) {
      const int col = wc * 64 + n * 16 + fr;
#pragma unroll
      for (int r = 0; r < 4; r++) {
        const int row = wr * 64 + m * 16 + kq * 4 + r;
        ub[row * 256 + col] = f2bf(accU[m][n][r]);
      }
    }
}

// =============== 256-row 8-wave gemm_bt (round-7 proven form) =================
#define SA(p, h, l, T) \
  gl_lds16(gA + (long)((h) * 128 + (l) * 64) * lda + (T) * 64, \
           dA + (p) * 32768 + (h) * 16384 + (l) * 8192)
#define SB(p, h, l, T) \
  gl_lds16(gB + (long)((h) * 128 + (l) * 64) * ldb + (T) * 64, \
           dB + (p) * (BNH * 16384) + (h) * 16384 + (l) * 8192)
#define RD_A(p, mh) { _Pragma("unroll") for (int m = 0; m < 4; m++) { \
    afr[m][0] = *(const bf16x8*)(lds + (p) * 32768 + aoffb + ((mh) * 64 + m * 16) * 128 + sb0); \
    afr[m][1] = *(const bf16x8*)(lds + (p) * 32768 + aoffb + ((mh) * 64 + m * 16) * 128 + sb1); } }
#define RD_B(p, nh, BF) { _Pragma("unroll") for (int n = 0; n < 2; n++) { \
    BF[n][0] = *(const bf16x8*)(lds + (p) * (BNH * 16384) + boffb + (((nh) * 2 + n) * 16) * 128 + sb0); \
    BF[n][1] = *(const bf16x8*)(lds + (p) * (BNH * 16384) + boffb + (((nh) * 2 + n) * 16) * 128 + sb1); } }
#define MFMA_QUAD(mh, nh, BF) { \
  _Pragma("unroll") for (int m = 0; m < 4; m++) \
  _Pragma("unroll") for (int n = 0; n < 2; n++) \
  _Pragma("unroll") for (int kk = 0; kk < 2; kk++) \
    acc[(mh) * 4 + m][(nh) * 2 + n] = MF(afr[m][kk], BF[n][kk], \
                                         acc[(mh) * 4 + m][(nh) * 2 + n]); }
#define BAR_MFMA_OPEN() \
  __builtin_amdgcn_sched_barrier(0); \
  __builtin_amdgcn_s_barrier(); \
  asm volatile("s_waitcnt lgkmcnt(0)" ::: "memory"); \
  __builtin_amdgcn_sched_barrier(0); \
  __builtin_amdgcn_s_setprio(1)
#define PH_CLOSE() \
  __builtin_amdgcn_s_setprio(0); \
  __builtin_amdgcn_sched_barrier(0); \
  __builtin_amdgcn_s_barrier(); \
  __builtin_amdgcn_sched_barrier(0)
#define PH_CLOSE_VM(N) \
  __builtin_amdgcn_s_setprio(0); \
  asm volatile("s_waitcnt vmcnt(" #N ")" ::: "memory"); \
  __builtin_amdgcn_sched_barrier(0); \
  __builtin_amdgcn_s_barrier(); \
  __builtin_amdgcn_sched_barrier(0)

template <int BNH, int OUT_BF16, int BIAS_MODE, int FUSE>
__global__ __launch_bounds__(512, 2) void k_gemm256(
    const u16* __restrict__ A, const u16* __restrict__ BT,
    void* __restrict__ Cv, const float* __restrict__ bias,
    const float* __restrict__ finv,
    int K, int lda, int ldb, int ldc, long sA, long sB, long sC, float scale) {
  __shared__ __align__(16) char lds[65536 + BNH * 32768 + 1024];
  float* part = (float*)(lds + 65536 + BNH * 32768);

  int bxi = blockIdx.x, byi = blockIdx.y, bzi = blockIdx.z;
  xcd_swz(bxi, byi, bzi);
  const int tid = threadIdx.x, lane = tid & 63, wid = tid >> 6;
  const int wr = wid >> 2, wc = wid & 3;
  const int fr = lane & 15, kq = lane >> 4, fr7 = fr & 7;
  const int brow = byi * 256, bcol = bxi * (BNH * 128);
  const long z = bzi;

  if (FUSE == 3 && tid < 256) part[tid] = finv[z * 2048 + brow + tid];

  const int srow = tid >> 3;
  const int sslot = (tid & 7) ^ (srow & 7);
  const u16* gA = A + z * sA + (long)(brow + srow) * lda + sslot * 8;
  const u16* gB = BT + z * sB + (long)(bcol + srow) * ldb + sslot * 8;
  char* dA = lds + tid * 16;
  char* dB = lds + 65536 + tid * 16;

  const int aoffb = (wr * 128 + fr) * 128;
  const int boffb = 65536 + (wc * (BNH * 32) + fr) * 128;
  const int sb0 = (kq ^ fr7) * 16;
  const int sb1 = ((4 + kq) ^ fr7) * 16;

  f32x4 acc[8][2 * BNH];
  const f32x4 zero = {0.f, 0.f, 0.f, 0.f};
#pragma unroll
  for (int m = 0; m < 8; m++)
#pragma unroll
    for (int n = 0; n < 2 * BNH; n++) acc[m][n] = zero;

  bf16x8 afr[4][2], bf0[2][2], bf1[2][2];
  const int iters = K >> 7;

  if (BNH == 2) {
    SA(0, 0, 0, 0); SA(0, 0, 1, 0); SA(0, 1, 0, 0); SA(0, 1, 1, 0);
    SB(0, 0, 0, 0); SB(0, 0, 1, 0); SB(0, 1, 0, 0); SB(0, 1, 1, 0);
    SB(1, 0, 0, 1); SB(1, 0, 1, 1); SB(1, 1, 0, 1); SB(1, 1, 1, 1);
    asm volatile("s_waitcnt vmcnt(4)" ::: "memory");
    __builtin_amdgcn_sched_barrier(0);
    __builtin_amdgcn_s_barrier();
    for (int i = 0; i < iters; i++) {
      const int t1 = 2 * i + 1, p0 = 2 * i + 2, p1 = 2 * i + 3;
      const bool more = (i + 1 < iters);
      RD_A(0, 0); RD_B(0, 0, bf0);
      SA(1, 0, 0, t1); SA(1, 0, 1, t1);
      BAR_MFMA_OPEN(); MFMA_QUAD(0, 0, bf0); PH_CLOSE();
      RD_B(0, 1, bf1);
      SA(1, 1, 0, t1); SA(1, 1, 1, t1);
      BAR_MFMA_OPEN(); MFMA_QUAD(0, 1, bf1); PH_CLOSE();
      RD_A(0, 1);
      if (more) { SB(0, 0, 0, p0); SB(0, 0, 1, p0); }
      BAR_MFMA_OPEN(); MFMA_QUAD(1, 0, bf0); PH_CLOSE();
      if (more) { SB(0, 1, 0, p0); SB(0, 1, 1, p0); }
      BAR_MFMA_OPEN(); MFMA_QUAD(1, 1, bf1);
      if (more) { PH_CLOSE_VM(4); } else { PH_CLOSE_VM(0); }
      RD_A(1, 0); RD_B(1, 0, bf0);
      if (more) { SA(0, 0, 0, p0); SA(0, 0, 1, p0); }
      BAR_MFMA_OPEN(); MFMA_QUAD(0, 0, bf0); PH_CLOSE();
      RD_B(1, 1, bf1);
      if (more) { SA(0, 1, 0, p0); SA(0, 1, 1, p0); }
      BAR_MFMA_OPEN(); MFMA_QUAD(0, 1, bf1); PH_CLOSE();
      RD_A(1, 1);
      if (more) { SB(1, 0, 0, p1); SB(1, 0, 1, p1); }
      BAR_MFMA_OPEN(); MFMA_QUAD(1, 0, bf0); PH_CLOSE();
      if (more) { SB(1, 1, 0, p1); SB(1, 1, 1, p1); }
      BAR_MFMA_OPEN(); MFMA_QUAD(1, 1, bf1);
      if (more) { PH_CLOSE_VM(4); } else { PH_CLOSE_VM(0); }
    }
  } else {
    SA(0, 0, 0, 0); SA(0, 0, 1, 0); SA(0, 1, 0, 0); SA(0, 1, 1, 0);
    SB(0, 0, 0, 0); SB(0, 0, 1, 0);
    SB(1, 0, 0, 1); SB(1, 0, 1, 1);
    asm volatile("s_waitcnt vmcnt(2)" ::: "memory");
    __builtin_amdgcn_sched_barrier(0);
    __builtin_amdgcn_s_barrier();
    for (int i = 0; i < iters; i++) {
      const int t1 = 2 * i + 1, p0 = 2 * i + 2, p1 = 2 * i + 3;
      const bool more = (i + 1 < iters);
      RD_A(0, 0); RD_B(0, 0, bf0);
      SA(1, 0, 0, t1); SA(1, 0, 1, t1);
      BAR_MFMA_OPEN(); MFMA_QUAD(0, 0, bf0); PH_CLOSE();
      RD_A(0, 1);
      SA(1, 1, 0, t1); SA(1, 1, 1, t1);
      if (more) { SB(0, 0, 0, p0); SB(0, 0, 1, p0); }
      BAR_MFMA_OPEN(); MFMA_QUAD(1, 0, bf0);
      if (more) { PH_CLOSE_VM(2); } else { PH_CLOSE_VM(0); }
      RD_A(1, 0); RD_B(1, 0, bf1);
      if (more) { SA(0, 0, 0, p0); SA(0, 0, 1, p0); }
      BAR_MFMA_OPEN(); MFMA_QUAD(0, 0, bf1); PH_CLOSE();
      RD_A(1, 1);
      if (more) { SA(0, 1, 0, p0); SA(0, 1, 1, p0);
                  SB(1, 0, 0, p1); SB(1, 0, 1, p1); }
      BAR_MFMA_OPEN(); MFMA_QUAD(1, 0, bf1);
      if (more) { PH_CLOSE_VM(2); } else { PH_CLOSE_VM(0); }
    }
  }

  const long zC = z * sC;
#pragma unroll
  for (int mi = 0; mi < 8; mi++) {
    const int r0 = brow + wr * 128 + mi * 16 + kq * 4;
#pragma unroll
    for (int n = 0; n < 2 * BNH; n++) {
      const int c = bcol + wc * (BNH * 32) + n * 16 + fr;
#pragma unroll
      for (int r = 0; r < 4; r++) {
        float v = acc[mi][n][r] * scale;
        if (BIAS_MODE == 1) v += bias[c];
        if (BIAS_MODE == 2) v += bias[r0 + r];
        if (FUSE == 3) v = v * part[r0 + r - brow] + bias[c];
        const long off = zC + (long)(r0 + r) * ldc + c;
        if (OUT_BF16) ((u16*)Cv)[off] = f2bf(v);
        else          ((float*)Cv)[off] = v;
      }
    }
  }
}

extern "C" void kernel_launch(void* const* d_in, const int* in_sizes, int n_in,
                              void* d_out, int out_size, void* d_ws, size_t ws_size,
                              hipStream_t stream) {
  (void)in_sizes; (void)n_in; (void)out_size;
  const float* in1 = (const float*)d_in[0];
  const float* in2 = (const float*)d_in[1];
  const float* Wq  = (const float*)d_in[2];
  const float* bq  = (const float*)d_in[3];
  const float* Wk  = (const float*)d_in[4];
  const float* Wv  = (const float*)d_in[6];
  const float* bv  = (const float*)d_in[7];
  float* out = (float*)d_out;

  const size_t MB = 1024ull * 1024ull;
  if (ws_size < 100 * MB) return;

  char* ws = (char*)d_ws;
  u16* A1   = (u16*)(ws + 0);                 // [32768][512] bf16 X1
  u16* A2   = (u16*)(ws + 32 * MB);           // [32768][256] bf16 X2
  u16* Qp   = (u16*)(ws + 48 * MB);           // [32768][256] Q'
  u16* TX2  = (u16*)(ws + 64 * MB);           // [16][256][2048] X2^T
  u16* U    = (u16*)(ws + 80 * MB);           // [32768][256] P~·X2
  u16* Wqb  = (u16*)(ws + 96 * MB);           // [512][512]
  u16* Wkb  = (u16*)(ws + 96 * MB + 524288);  // [256][512]
  u16* WvT  = (u16*)(ws + 96 * MB + 786432);  // [512][256]
  u16* WT1  = (u16*)(ws + 97 * MB);           // [256][512] Wk·Wq^T
  float* bqp = (float*)(ws + 97 * MB + 262144);   // [256]
  float* Iv  = (float*)(ws + 97 * MB + 524288);   // [32768] inv row sums

  k_cvt<<<2048, 256, 0, stream>>>(in1, A1, 32768 * 512 / 4);
  k_cvt<<<256, 256, 0, stream>>>(Wq, Wqb, 512 * 512 / 4);
  k_cvt<<<128, 256, 0, stream>>>(Wk, Wkb, 256 * 512 / 4);
  k_cvt_t<<<dim3(8, 64, 16), dim3(32, 8), 0, stream>>>(in2, A2, TX2);
  k_transpose<<<dim3(16, 8), dim3(32, 8), 0, stream>>>(Wv, WvT, LENL, DIMD);
  // W' = Wk·Wq^T ; bq' = bq·Wk^T
  k_gemm256<2, 1, 0, 0><<<dim3(2, 1, 1), 512, 0, stream>>>(
      Wkb, Wqb, WT1, nullptr, nullptr, 512, 512, 512, 512, 0, 0, 0, 1.f);
  k_bqp<<<1, 256, 0, stream>>>(bq, Wk, bqp);
  // Q' = X1·W'^T + bq'
  k_gemm256<1, 1, 1, 0><<<dim3(2, 128, 1), 512, 0, stream>>>(
      A1, WT1, Qp, bqp, nullptr, 512, 512, 512, 256, 0, 0, 0, 1.f);
  // fused: S~ = exp(Q'·X2^T/sqrt(512)); U = S~·X2; Iv = 1/rowsum
  const float qk_scale = 0.044194173824159216f;
  k_fused_su<<<dim3(16, 16), 512, 0, stream>>>(Qp, A2, TX2, U, Iv, qk_scale);
  // out = Iv·(U·WvT^T) + bv
  k_gemm256<2, 0, 0, 3><<<dim3(2, 128, 1), 512, 0, stream>>>(
      U, WvT, out, bv, Iv, 256, 256, 256, 512, 0, 0, 0, 1.f);
}

// Round 16
// 185.398 us; speedup vs baseline: 1.2809x; 1.0049x over previous
//
#include <hip/hip_runtime.h>

// CrossAttention B=16, N1=N2=2048, D=512, L=256 — algebraic restructure +
// fused S~/U kernel (QK(i) || PV(i-1) pipeline, counted vmcnt(8), S dbuf,
// 64-key geometry). Round 16 = round-15 verified state + vectorized
// conversion kernels (16B stores in k_cvt; k_cvt_t rewritten with ushort2 /
// int4 stores) — the cvt pre-passes were store-granularity-bound.
//   W' = Wk·Wq^T, bq' = bq·Wk^T; Q' = X1·W'^T + bq'
//   fused: S = exp(Q'·X2^T/sqrt(512)) (LDS only), U = S·X2, Iv = 1/rowsum
//   out = Iv·(U·Wv) + bv

#define DIMD 512
#define LENL 256
#define BATCH 16
#define NQ 2048
#define NKV 2048

using bf16x8 = __attribute__((ext_vector_type(8))) __bf16;
using f32x4  = __attribute__((ext_vector_type(4))) float;
typedef unsigned short u16;

__device__ __forceinline__ u16 f2bf(float f) {
  union { float f; unsigned u; } x; x.f = f;
  return (u16)((x.u + 0x7fffu + ((x.u >> 16) & 1u)) >> 16);
}
__device__ __forceinline__ float bf2f(u16 b) {
  union { unsigned u; float f; } x; x.u = ((unsigned)b) << 16;
  return x.f;
}

// ---- fp32 -> bf16, 8 elems/thread/iter, 16B stores ----
__global__ __launch_bounds__(256) void k_cvt(const float* __restrict__ src,
                                             u16* __restrict__ dst, int n8) {
  int i = blockIdx.x * blockDim.x + threadIdx.x;
  int stride = gridDim.x * blockDim.x;
  for (; i < n8; i += stride) {
    float4 a = ((const float4*)src)[2 * i];
    float4 b = ((const float4*)src)[2 * i + 1];
    int4 o;
    o.x = (int)((unsigned)f2bf(a.x) | ((unsigned)f2bf(a.y) << 16));
    o.y = (int)((unsigned)f2bf(a.z) | ((unsigned)f2bf(a.w) << 16));
    o.z = (int)((unsigned)f2bf(b.x) | ((unsigned)f2bf(b.y) << 16));
    o.w = (int)((unsigned)f2bf(b.z) | ((unsigned)f2bf(b.w) << 16));
    ((int4*)dst)[i] = o;
  }
}

__global__ __launch_bounds__(256) void k_transpose(const float* __restrict__ W,
                                                   u16* __restrict__ WT,
                                                   int K, int N) {
  __shared__ float t[32][33];
  int bx = blockIdx.x * 32;
  int by = blockIdx.y * 32;
  int tx = threadIdx.x, ty = threadIdx.y;  // (32,8)
#pragma unroll
  for (int i = 0; i < 4; i++)
    t[ty + 8 * i][tx] = W[(size_t)(by + ty + 8 * i) * N + (bx + tx)];
  __syncthreads();
#pragma unroll
  for (int i = 0; i < 4; i++)
    WT[(size_t)(bx + ty + 8 * i) * K + (by + tx)] = f2bf(t[tx][ty + 8 * i]);
}

// fused: in2 f32 [z][2048][256] -> A2 bf16 (same layout) + TX2 bf16
// [z][256][2048]. Tile 32 keys x 64 L-cols; phase-1 float2 reads + ushort2
// A2 stores; phase-2 int4 (8-key) TX2 stores from padded LDS tile.
__global__ __launch_bounds__(256) void k_cvt_t(const float* __restrict__ in2,
                                               u16* __restrict__ A2,
                                               u16* __restrict__ TX2) {
  __shared__ u16 t[64][36];  // [col][key], padded
  const int bx = blockIdx.x * 64;  // L base
  const int by = blockIdx.y * 32;  // key base
  const long z = blockIdx.z;
  const float* s = in2 + z * (2048L * 256);
  u16* a = A2 + z * (2048L * 256);
  u16* d = TX2 + z * (256L * 2048);
  const int tx = threadIdx.x, ty = threadIdx.y;  // (32,8)
#pragma unroll
  for (int i = 0; i < 4; i++) {
    const int row = by + ty + 8 * i;
    const float2 v = *(const float2*)&s[(size_t)row * 256 + bx + 2 * tx];
    const u16 e0 = f2bf(v.x), e1 = f2bf(v.y);
    *(unsigned*)&a[(size_t)row * 256 + bx + 2 * tx] =
        (unsigned)e0 | ((unsigned)e1 << 16);
    t[2 * tx][ty + 8 * i] = e0;
    t[2 * tx + 1][ty + 8 * i] = e1;
  }
  __syncthreads();
  const int tid = ty * 32 + tx;
  const int col = tid >> 2, kc = (tid & 3) * 8;
  const u16* pr = &t[col][kc];
  int4 w;
  w.x = (int)((unsigned)pr[0] | ((unsigned)pr[1] << 16));
  w.y = (int)((unsigned)pr[2] | ((unsigned)pr[3] << 16));
  w.z = (int)((unsigned)pr[4] | ((unsigned)pr[5] << 16));
  w.w = (int)((unsigned)pr[6] | ((unsigned)pr[7] << 16));
  *(int4*)&d[(size_t)(bx + col) * 2048 + by + kc] = w;
}

__global__ __launch_bounds__(256) void k_bqp(const float* __restrict__ bq,
                                             const float* __restrict__ Wk,
                                             float* __restrict__ bqp) {
  int n = threadIdx.x;
  float s = 0.f;
  for (int o = 0; o < 512; o += 4) {
    float4 w = *(const float4*)&Wk[(size_t)n * 512 + o];
    float4 b = *(const float4*)&bq[o];
    s += w.x * b.x + w.y * b.y + w.z * b.z + w.w * b.w;
  }
  bqp[n] = s;
}

__device__ __forceinline__ void gl_lds16(const void* g, void* l) {
  __builtin_amdgcn_global_load_lds(
      (const __attribute__((address_space(1))) void*)g,
      (__attribute__((address_space(3))) void*)l, 16, 0, 0);
}

__device__ __forceinline__ void xcd_swz(int& bx, int& by, int& bz) {
  const int nx = gridDim.x, ny = gridDim.y, nz = gridDim.z;
  const long nwg = (long)nx * ny * nz;
  if (nwg & 7) return;
  long lin = (long)bx + (long)nx * ((long)by + (long)ny * bz);
  const long q = nwg >> 3;
  const long nl = (lin & 7) * q + (lin >> 3);
  bx = (int)(nl % nx);
  long r2 = nl / nx;
  by = (int)(r2 % ny);
  bz = (int)(r2 / ny);
}

#define MF(a, b, c) __builtin_amdgcn_mfma_f32_16x16x32_bf16(a, b, c, 0, 0, 0)

// ================== fused S~ / U kernel (QK || PV pipeline) ==================
// LDS: X2 dbuf 2x32K [0,64K) | TX2 dbuf 2x32K [64K,128K) | S dbuf 2x16K
// [128K,160K). part aliases S[0] (post-loop only). 160 KiB total, 1 block/CU.
__global__ __launch_bounds__(512, 2) void k_fused_su(
    const u16* __restrict__ Qp, const u16* __restrict__ X2g,
    const u16* __restrict__ TXg, u16* __restrict__ U,
    float* __restrict__ Iv, float scale) {
  __shared__ __align__(16) char lds[163840];
  float* part = (float*)(lds + 131072);  // aliases S[0]; used only post-loop

  int bxi = blockIdx.x, byi = blockIdx.y, bzi = blockIdx.z;
  xcd_swz(bxi, byi, bzi);
  const int tid = threadIdx.x, lane = tid & 63, wid = tid >> 6;
  const int fr = lane & 15, kq = lane >> 4, fr7 = fr & 7;
  const int row0 = bxi * 128;
  const long z = byi;
  const int kh = wid & 1, rq = wid >> 1;  // QK: 32 keys x 32 rows per wave
  const int wr = wid >> 2, wc = wid & 3;  // PV: 64 rows x 64 cols per wave

  bf16x8 qf[2][8];
  {
    const u16* qb = Qp + ((long)z * 2048 + row0 + rq * 32) * 256;
#pragma unroll
    for (int ni = 0; ni < 2; ni++)
#pragma unroll
      for (int kk = 0; kk < 8; kk++)
        qf[ni][kk] =
            *(const bf16x8*)(qb + (ni * 16 + fr) * 256 + kk * 32 + kq * 8);
  }

  const u16* gX2 = X2g + (long)z * (2048 * 256);
  const u16* gTX = TXg + (long)z * (256 * 2048);
  const int xrow = tid >> 5, xs = tid & 31;  // X2 tile: 64 rows x 512B
  const int trow = tid >> 3, ts = tid & 7;   // TX2 tile: 256 rows x 128B

#define STG_X2(ii, b) { \
  _Pragma("unroll") for (int p = 0; p < 4; p++) { \
    const int r_ = p * 16 + xrow; \
    gl_lds16(gX2 + ((long)(ii) * 64 + r_) * 256 + (xs ^ (r_ & 7)) * 8, \
             lds + (b) * 32768 + (p * 512 + tid) * 16); } }
#define STG_TX(ii, b) { \
  _Pragma("unroll") for (int p = 0; p < 4; p++) { \
    const int r_ = p * 64 + trow; \
    gl_lds16(gTX + (long)r_ * 2048 + (ii) * 64 + (ts ^ (r_ & 7)) * 8, \
             lds + 65536 + (b) * 32768 + (p * 512 + tid) * 16); } }

#define QK_BODY(xbuf, sbuf) { \
  f32x4 accS[2][2]; \
  accS[0][0] = zero; accS[0][1] = zero; accS[1][0] = zero; accS[1][1] = zero; \
  const char* xb = lds + (xbuf) * 32768; \
  _Pragma("unroll") for (int kk = 0; kk < 8; kk++) { \
    const int so = ((kk * 4 + kq) ^ fr7) << 4; \
    bf16x8 xf0 = *(const bf16x8*)(xb + (kh * 32 + fr) * 512 + so); \
    bf16x8 xf1 = *(const bf16x8*)(xb + (kh * 32 + 16 + fr) * 512 + so); \
    accS[0][0] = MF(xf0, qf[0][kk], accS[0][0]); \
    accS[0][1] = MF(xf0, qf[1][kk], accS[0][1]); \
    accS[1][0] = MF(xf1, qf[0][kk], accS[1][0]); \
    accS[1][1] = MF(xf1, qf[1][kk], accS[1][1]); \
  } \
  _Pragma("unroll") for (int mi = 0; mi < 2; mi++) \
  _Pragma("unroll") for (int ni = 0; ni < 2; ni++) { \
    u16 e[4]; float sum4 = 0.f; \
    _Pragma("unroll") for (int r = 0; r < 4; r++) { \
      float v = accS[mi][ni][r] * scale; \
      float ef = __expf(fminf(v, 30.f)); \
      e[r] = f2bf(ef); sum4 += bf2f(e[r]); \
    } \
    if (ni == 0) rs0 += sum4; else rs1 += sum4; \
    unsigned long long w = \
        (unsigned long long)((unsigned)e[0] | ((unsigned)e[1] << 16)) | \
        ((unsigned long long)((unsigned)e[2] | ((unsigned)e[3] << 16)) << 32); \
    const int row = rq * 32 + ni * 16 + fr; \
    const int inrow = (kh * 64 + mi * 32 + kq * 8) ^ (fr7 << 4); \
    *(unsigned long long*)(lds + 131072 + (sbuf) * 16384 + row * 128 + inrow) = w; \
  } }

#define PV_BODY(tbuf, sbuf) { \
  const char* tb = lds + 65536 + (tbuf) * 32768; \
  const char* sbase = lds + 131072 + (sbuf) * 16384; \
  _Pragma("unroll") for (int kk = 0; kk < 2; kk++) { \
    const int so = ((kk * 4 + kq) ^ fr7) << 4; \
    bf16x8 sf[4], tf[4]; \
    _Pragma("unroll") for (int m = 0; m < 4; m++) \
      sf[m] = *(const bf16x8*)(sbase + (wr * 64 + m * 16 + fr) * 128 + so); \
    _Pragma("unroll") for (int n = 0; n < 4; n++) \
      tf[n] = *(const bf16x8*)(tb + (wc * 64 + n * 16 + fr) * 128 + so); \
    _Pragma("unroll") for (int m = 0; m < 4; m++) \
    _Pragma("unroll") for (int n = 0; n < 4; n++) \
      accU[m][n] = MF(sf[m], tf[n], accU[m][n]); \
  } }

  f32x4 accU[4][4];
  const f32x4 zero = {0.f, 0.f, 0.f, 0.f};
#pragma unroll
  for (int m = 0; m < 4; m++)
#pragma unroll
    for (int n = 0; n < 4; n++) accU[m][n] = zero;
  float rs0 = 0.f, rs1 = 0.f;

  // prologue: X2(0), X2(1), TX2(0) = 12 ops in flight
  STG_X2(0, 0); STG_X2(1, 1); STG_TX(0, 0);
  asm volatile("s_waitcnt vmcnt(8)" ::: "memory");  // X2(0) landed
  __builtin_amdgcn_sched_barrier(0);
  __builtin_amdgcn_s_barrier();
  __builtin_amdgcn_s_setprio(1);
  QK_BODY(0, 0);
  __builtin_amdgcn_s_setprio(0);
  asm volatile("s_waitcnt lgkmcnt(0)" ::: "memory");
  __builtin_amdgcn_sched_barrier(0);
  __builtin_amdgcn_s_barrier();
  __builtin_amdgcn_sched_barrier(0);

  for (int i = 1; i < 32; i++) {
    const int cur = i & 1, prv = cur ^ 1;
    const int pre = (i + 1 > 31) ? 31 : i + 1;  // dup-stage keeps count uniform
    STG_X2(pre, (i + 1) & 1);                   // dup target is a dead buffer
    STG_TX(i, cur);
    asm volatile("s_waitcnt vmcnt(8)" ::: "memory");  // X2(i), TX2(i-1) landed
    __builtin_amdgcn_sched_barrier(0);
    __builtin_amdgcn_s_barrier();
    __builtin_amdgcn_sched_barrier(0);
    __builtin_amdgcn_s_setprio(1);
    QK_BODY(cur, cur);   // independent of PV below: compiler interleaves
    PV_BODY(prv, prv);
    __builtin_amdgcn_s_setprio(0);
    asm volatile("s_waitcnt lgkmcnt(0)" ::: "memory");
    __builtin_amdgcn_sched_barrier(0);
    __builtin_amdgcn_s_barrier();
    __builtin_amdgcn_sched_barrier(0);
  }

  asm volatile("s_waitcnt vmcnt(0)" ::: "memory");
  __builtin_amdgcn_sched_barrier(0);
  __builtin_amdgcn_s_barrier();
  __builtin_amdgcn_s_setprio(1);
  PV_BODY(1, 1);
  __builtin_amdgcn_s_setprio(0);

#undef STG_X2
#undef STG_TX
#undef QK_BODY
#undef PV_BODY

  // rowsums -> Iv (part aliases S[0]; S is dead now)
  __syncthreads();
  if (tid < 128) part[tid] = 0.f;
  __syncthreads();
  {
    float s0 = rs0, s1 = rs1;
    s0 += __shfl_xor(s0, 16); s0 += __shfl_xor(s0, 32);
    s1 += __shfl_xor(s1, 16); s1 += __shfl_xor(s1, 32);
    if (lane < 16) {
      atomicAdd(&part[rq * 32 + lane], s0);
      atomicAdd(&part[rq * 32 + 16 + lane], s1);
    }
  }
  __syncthreads();
  if (tid < 128) Iv[z * 2048 + row0 + tid] = 1.f / part[tid];

  // U store (unnormalized bf16; out-GEMM applies Iv)
  u16* ub = U + ((long)z * 2048 + row0) * 256;
#pragma unroll
  for (int m = 0; m < 4; m++)
#pragma unroll
    for (int n = 0; n < 4; n++) {
      const int col = wc * 64 + n * 16 + fr;
#pragma unroll
      for (int r = 0; r < 4; r++) {
        const int row = wr * 64 + m * 16 + kq * 4 + r;
        ub[row * 256 + col] = f2bf(accU[m][n][r]);
      }
    }
}

// =============== 256-row 8-wave gemm_bt (round-7 proven form) =================
#define SA(p, h, l, T) \
  gl_lds16(gA + (long)((h) * 128 + (l) * 64) * lda + (T) * 64, \
           dA + (p) * 32768 + (h) * 16384 + (l) * 8192)
#define SB(p, h, l, T) \
  gl_lds16(gB + (long)((h) * 128 + (l) * 64) * ldb + (T) * 64, \
           dB + (p) * (BNH * 16384) + (h) * 16384 + (l) * 8192)
#define RD_A(p, mh) { _Pragma("unroll") for (int m = 0; m < 4; m++) { \
    afr[m][0] = *(const bf16x8*)(lds + (p) * 32768 + aoffb + ((mh) * 64 + m * 16) * 128 + sb0); \
    afr[m][1] = *(const bf16x8*)(lds + (p) * 32768 + aoffb + ((mh) * 64 + m * 16) * 128 + sb1); } }
#define RD_B(p, nh, BF) { _Pragma("unroll") for (int n = 0; n < 2; n++) { \
    BF[n][0] = *(const bf16x8*)(lds + (p) * (BNH * 16384) + boffb + (((nh) * 2 + n) * 16) * 128 + sb0); \
    BF[n][1] = *(const bf16x8*)(lds + (p) * (BNH * 16384) + boffb + (((nh) * 2 + n) * 16) * 128 + sb1); } }
#define MFMA_QUAD(mh, nh, BF) { \
  _Pragma("unroll") for (int m = 0; m < 4; m++) \
  _Pragma("unroll") for (int n = 0; n < 2; n++) \
  _Pragma("unroll") for (int kk = 0; kk < 2; kk++) \
    acc[(mh) * 4 + m][(nh) * 2 + n] = MF(afr[m][kk], BF[n][kk], \
                                         acc[(mh) * 4 + m][(nh) * 2 + n]); }
#define BAR_MFMA_OPEN() \
  __builtin_amdgcn_sched_barrier(0); \
  __builtin_amdgcn_s_barrier(); \
  asm volatile("s_waitcnt lgkmcnt(0)" ::: "memory"); \
  __builtin_amdgcn_sched_barrier(0); \
  __builtin_amdgcn_s_setprio(1)
#define PH_CLOSE() \
  __builtin_amdgcn_s_setprio(0); \
  __builtin_amdgcn_sched_barrier(0); \
  __builtin_amdgcn_s_barrier(); \
  __builtin_amdgcn_sched_barrier(0)
#define PH_CLOSE_VM(N) \
  __builtin_amdgcn_s_setprio(0); \
  asm volatile("s_waitcnt vmcnt(" #N ")" ::: "memory"); \
  __builtin_amdgcn_sched_barrier(0); \
  __builtin_amdgcn_s_barrier(); \
  __builtin_amdgcn_sched_barrier(0)

template <int BNH, int OUT_BF16, int BIAS_MODE, int FUSE>
__global__ __launch_bounds__(512, 2) void k_gemm256(
    const u16* __restrict__ A, const u16* __restrict__ BT,
    void* __restrict__ Cv, const float* __restrict__ bias,
    const float* __restrict__ finv,
    int K, int lda, int ldb, int ldc, long sA, long sB, long sC, float scale) {
  __shared__ __align__(16) char lds[65536 + BNH * 32768 + 1024];
  float* part = (float*)(lds + 65536 + BNH * 32768);

  int bxi = blockIdx.x, byi = blockIdx.y, bzi = blockIdx.z;
  xcd_swz(bxi, byi, bzi);
  const int tid = threadIdx.x, lane = tid & 63, wid = tid >> 6;
  const int wr = wid >> 2, wc = wid & 3;
  const int fr = lane & 15, kq = lane >> 4, fr7 = fr & 7;
  const int brow = byi * 256, bcol = bxi * (BNH * 128);
  const long z = bzi;

  if (FUSE == 3 && tid < 256) part[tid] = finv[z * 2048 + brow + tid];

  const int srow = tid >> 3;
  const int sslot = (tid & 7) ^ (srow & 7);
  const u16* gA = A + z * sA + (long)(brow + srow) * lda + sslot * 8;
  const u16* gB = BT + z * sB + (long)(bcol + srow) * ldb + sslot * 8;
  char* dA = lds + tid * 16;
  char* dB = lds + 65536 + tid * 16;

  const int aoffb = (wr * 128 + fr) * 128;
  const int boffb = 65536 + (wc * (BNH * 32) + fr) * 128;
  const int sb0 = (kq ^ fr7) * 16;
  const int sb1 = ((4 + kq) ^ fr7) * 16;

  f32x4 acc[8][2 * BNH];
  const f32x4 zero = {0.f, 0.f, 0.f, 0.f};
#pragma unroll
  for (int m = 0; m < 8; m++)
#pragma unroll
    for (int n = 0; n < 2 * BNH; n++) acc[m][n] = zero;

  bf16x8 afr[4][2], bf0[2][2], bf1[2][2];
  const int iters = K >> 7;

  if (BNH == 2) {
    SA(0, 0, 0, 0); SA(0, 0, 1, 0); SA(0, 1, 0, 0); SA(0, 1, 1, 0);
    SB(0, 0, 0, 0); SB(0, 0, 1, 0); SB(0, 1, 0, 0); SB(0, 1, 1, 0);
    SB(1, 0, 0, 1); SB(1, 0, 1, 1); SB(1, 1, 0, 1); SB(1, 1, 1, 1);
    asm volatile("s_waitcnt vmcnt(4)" ::: "memory");
    __builtin_amdgcn_sched_barrier(0);
    __builtin_amdgcn_s_barrier();
    for (int i = 0; i < iters; i++) {
      const int t1 = 2 * i + 1, p0 = 2 * i + 2, p1 = 2 * i + 3;
      const bool more = (i + 1 < iters);
      RD_A(0, 0); RD_B(0, 0, bf0);
      SA(1, 0, 0, t1); SA(1, 0, 1, t1);
      BAR_MFMA_OPEN(); MFMA_QUAD(0, 0, bf0); PH_CLOSE();
      RD_B(0, 1, bf1);
      SA(1, 1, 0, t1); SA(1, 1, 1, t1);
      BAR_MFMA_OPEN(); MFMA_QUAD(0, 1, bf1); PH_CLOSE();
      RD_A(0, 1);
      if (more) { SB(0, 0, 0, p0); SB(0, 0, 1, p0); }
      BAR_MFMA_OPEN(); MFMA_QUAD(1, 0, bf0); PH_CLOSE();
      if (more) { SB(0, 1, 0, p0); SB(0, 1, 1, p0); }
      BAR_MFMA_OPEN(); MFMA_QUAD(1, 1, bf1);
      if (more) { PH_CLOSE_VM(4); } else { PH_CLOSE_VM(0); }
      RD_A(1, 0); RD_B(1, 0, bf0);
      if (more) { SA(0, 0, 0, p0); SA(0, 0, 1, p0); }
      BAR_MFMA_OPEN(); MFMA_QUAD(0, 0, bf0); PH_CLOSE();
      RD_B(1, 1, bf1);
      if (more) { SA(0, 1, 0, p0); SA(0, 1, 1, p0); }
      BAR_MFMA_OPEN(); MFMA_QUAD(0, 1, bf1); PH_CLOSE();
      RD_A(1, 1);
      if (more) { SB(1, 0, 0, p1); SB(1, 0, 1, p1); }
      BAR_MFMA_OPEN(); MFMA_QUAD(1, 0, bf0); PH_CLOSE();
      if (more) { SB(1, 1, 0, p1); SB(1, 1, 1, p1); }
      BAR_MFMA_OPEN(); MFMA_QUAD(1, 1, bf1);
      if (more) { PH_CLOSE_VM(4); } else { PH_CLOSE_VM(0); }
    }
  } else {
    SA(0, 0, 0, 0); SA(0, 0, 1, 0); SA(0, 1, 0, 0); SA(0, 1, 1, 0);
    SB(0, 0, 0, 0); SB(0, 0, 1, 0);
    SB(1, 0, 0, 1); SB(1, 0, 1, 1);
    asm volatile("s_waitcnt vmcnt(2)" ::: "memory");
    __builtin_amdgcn_sched_barrier(0);
    __builtin_amdgcn_s_barrier();
    for (int i = 0; i < iters; i++) {
      const int t1 = 2 * i + 1, p0 = 2 * i + 2, p1 = 2 * i + 3;
      const bool more = (i + 1 < iters);
      RD_A(0, 0); RD_B(0, 0, bf0);
      SA(1, 0, 0, t1); SA(1, 0, 1, t1);
      BAR_MFMA_OPEN(); MFMA_QUAD(0, 0, bf0); PH_CLOSE();
      RD_A(0, 1);
      SA(1, 1, 0, t1); SA(1, 1, 1, t1);
      if (more) { SB(0, 0, 0, p0); SB(0, 0, 1, p0); }
      BAR_MFMA_OPEN(); MFMA_QUAD(1, 0, bf0);
      if (more) { PH_CLOSE_VM(2); } else { PH_CLOSE_VM(0); }
      RD_A(1, 0); RD_B(1, 0, bf1);
      if (more) { SA(0, 0, 0, p0); SA(0, 0, 1, p0); }
      BAR_MFMA_OPEN(); MFMA_QUAD(0, 0, bf1); PH_CLOSE();
      RD_A(1, 1);
      if (more) { SA(0, 1, 0, p0); SA(0, 1, 1, p0);
                  SB(1, 0, 0, p1); SB(1, 0, 1, p1); }
      BAR_MFMA_OPEN(); MFMA_QUAD(1, 0, bf1);
      if (more) { PH_CLOSE_VM(2); } else { PH_CLOSE_VM(0); }
    }
  }

  const long zC = z * sC;
#pragma unroll
  for (int mi = 0; mi < 8; mi++) {
    const int r0 = brow + wr * 128 + mi * 16 + kq * 4;
#pragma unroll
    for (int n = 0; n < 2 * BNH; n++) {
      const int c = bcol + wc * (BNH * 32) + n * 16 + fr;
#pragma unroll
      for (int r = 0; r < 4; r++) {
        float v = acc[mi][n][r] * scale;
        if (BIAS_MODE == 1) v += bias[c];
        if (BIAS_MODE == 2) v += bias[r0 + r];
        if (FUSE == 3) v = v * part[r0 + r - brow] + bias[c];
        const long off = zC + (long)(r0 + r) * ldc + c;
        if (OUT_BF16) ((u16*)Cv)[off] = f2bf(v);
        else          ((float*)Cv)[off] = v;
      }
    }
  }
}

extern "C" void kernel_launch(void* const* d_in, const int* in_sizes, int n_in,
                              void* d_out, int out_size, void* d_ws, size_t ws_size,
                              hipStream_t stream) {
  (void)in_sizes; (void)n_in; (void)out_size;
  const float* in1 = (const float*)d_in[0];
  const float* in2 = (const float*)d_in[1];
  const float* Wq  = (const float*)d_in[2];
  const float* bq  = (const float*)d_in[3];
  const float* Wk  = (const float*)d_in[4];
  const float* Wv  = (const float*)d_in[6];
  const float* bv  = (const float*)d_in[7];
  float* out = (float*)d_out;

  const size_t MB = 1024ull * 1024ull;
  if (ws_size < 100 * MB) return;

  char* ws = (char*)d_ws;
  u16* A1   = (u16*)(ws + 0);                 // [32768][512] bf16 X1
  u16* A2   = (u16*)(ws + 32 * MB);           // [32768][256] bf16 X2
  u16* Qp   = (u16*)(ws + 48 * MB);           // [32768][256] Q'
  u16* TX2  = (u16*)(ws + 64 * MB);           // [16][256][2048] X2^T
  u16* U    = (u16*)(ws + 80 * MB);           // [32768][256] P~·X2
  u16* Wqb  = (u16*)(ws + 96 * MB);           // [512][512]
  u16* Wkb  = (u16*)(ws + 96 * MB + 524288);  // [256][512]
  u16* WvT  = (u16*)(ws + 96 * MB + 786432);  // [512][256]
  u16* WT1  = (u16*)(ws + 97 * MB);           // [256][512] Wk·Wq^T
  float* bqp = (float*)(ws + 97 * MB + 262144);   // [256]
  float* Iv  = (float*)(ws + 97 * MB + 524288);   // [32768] inv row sums

  k_cvt<<<2048, 256, 0, stream>>>(in1, A1, 32768 * 512 / 8);
  k_cvt<<<128, 256, 0, stream>>>(Wq, Wqb, 512 * 512 / 8);
  k_cvt<<<64, 256, 0, stream>>>(Wk, Wkb, 256 * 512 / 8);
  k_cvt_t<<<dim3(4, 64, 16), dim3(32, 8), 0, stream>>>(in2, A2, TX2);
  k_transpose<<<dim3(16, 8), dim3(32, 8), 0, stream>>>(Wv, WvT, LENL, DIMD);
  // W' = Wk·Wq^T ; bq' = bq·Wk^T
  k_gemm256<2, 1, 0, 0><<<dim3(2, 1, 1), 512, 0, stream>>>(
      Wkb, Wqb, WT1, nullptr, nullptr, 512, 512, 512, 512, 0, 0, 0, 1.f);
  k_bqp<<<1, 256, 0, stream>>>(bq, Wk, bqp);
  // Q' = X1·W'^T + bq'
  k_gemm256<1, 1, 1, 0><<<dim3(2, 128, 1), 512, 0, stream>>>(
      A1, WT1, Qp, bqp, nullptr, 512, 512, 512, 256, 0, 0, 0, 1.f);
  // fused: S~ = exp(Q'·X2^T/sqrt(512)); U = S~·X2; Iv = 1/rowsum
  const float qk_scale = 0.044194173824159216f;
  k_fused_su<<<dim3(16, 16), 512, 0, stream>>>(Qp, A2, TX2, U, Iv, qk_scale);
  // out = Iv·(U·WvT^T) + bv
  k_gemm256<2, 0, 0, 3><<<dim3(2, 128, 1), 512, 0, stream>>>(
      U, WvT, out, bv, Iv, 256, 256, 256, 512, 0, 0, 0, 1.f);
}

// Round 17
// 171.818 us; speedup vs baseline: 1.3821x; 1.0790x over previous
//
#include <hip/hip_runtime.h>

// CrossAttention B=16, N1=N2=2048, D=512, L=256 — algebraic restructure +
// fused S~/U kernel (QK(i) || PV(i-1) pipeline, counted vmcnt(8), S dbuf,
// 64-key geometry). Round 17 = round-16 verified state with pre-pass kernels
// merged (11 -> 6 launches): k_prep = {cvt Wq, cvt Wk, transpose Wv, bqp},
// k_in = {cvt in1, cvt+transpose in2}. WT1 GEMM moved to BNH=1 (4 blocks).
//   W' = Wk·Wq^T, bq' = bq·Wk^T; Q' = X1·W'^T + bq'
//   fused: S = exp(Q'·X2^T/sqrt(512)) (LDS only), U = S·X2, Iv = 1/rowsum
//   out = Iv·(U·Wv) + bv

#define DIMD 512
#define LENL 256
#define BATCH 16
#define NQ 2048
#define NKV 2048

using bf16x8 = __attribute__((ext_vector_type(8))) __bf16;
using f32x4  = __attribute__((ext_vector_type(4))) float;
typedef unsigned short u16;

__device__ __forceinline__ u16 f2bf(float f) {
  union { float f; unsigned u; } x; x.f = f;
  return (u16)((x.u + 0x7fffu + ((x.u >> 16) & 1u)) >> 16);
}
__device__ __forceinline__ float bf2f(u16 b) {
  union { unsigned u; float f; } x; x.u = ((unsigned)b) << 16;
  return x.f;
}

__device__ __forceinline__ void cvt8(const float* __restrict__ src,
                                     u16* __restrict__ dst, int i) {
  float4 a = ((const float4*)src)[2 * i];
  float4 b = ((const float4*)src)[2 * i + 1];
  int4 o;
  o.x = (int)((unsigned)f2bf(a.x) | ((unsigned)f2bf(a.y) << 16));
  o.y = (int)((unsigned)f2bf(a.z) | ((unsigned)f2bf(a.w) << 16));
  o.z = (int)((unsigned)f2bf(b.x) | ((unsigned)f2bf(b.y) << 16));
  o.w = (int)((unsigned)f2bf(b.z) | ((unsigned)f2bf(b.w) << 16));
  ((int4*)dst)[i] = o;
}

// ---- merged weight prep: cvt Wq (128 blk), cvt Wk (64), transpose Wv (128),
// ---- bq' = bq·Wk^T (1)  => 321 blocks x 256 threads
__global__ __launch_bounds__(256) void k_prep(
    const float* __restrict__ Wq, const float* __restrict__ Wk,
    const float* __restrict__ Wv, const float* __restrict__ bq,
    u16* __restrict__ Wqb, u16* __restrict__ Wkb, u16* __restrict__ WvT,
    float* __restrict__ bqp) {
  __shared__ float t[32][33];
  const int b = blockIdx.x, tid = threadIdx.x;
  if (b < 128) {
    cvt8(Wq, Wqb, b * 256 + tid);                 // 512*512/8 = 32768
  } else if (b < 192) {
    cvt8(Wk, Wkb, (b - 128) * 256 + tid);         // 256*512/8 = 16384
  } else if (b < 320) {
    // transpose Wv[256][512] f32 -> WvT[512][256] bf16; tile (b-192)
    const int tb = b - 192;
    const int bx = (tb & 15) * 32;   // N dir (512)
    const int by = (tb >> 4) * 32;   // K dir (256)
    const int tx = tid & 31, ty = tid >> 5;  // (32,8)
#pragma unroll
    for (int i = 0; i < 4; i++)
      t[ty + 8 * i][tx] = Wv[(size_t)(by + ty + 8 * i) * 512 + (bx + tx)];
    __syncthreads();
#pragma unroll
    for (int i = 0; i < 4; i++)
      WvT[(size_t)(bx + ty + 8 * i) * 256 + (by + tx)] =
          f2bf(t[tx][ty + 8 * i]);
  } else {
    // bqp[n] = sum_o bq[o] * Wk[n][o]
    float s = 0.f;
    for (int o = 0; o < 512; o += 4) {
      float4 w = *(const float4*)&Wk[(size_t)tid * 512 + o];
      float4 v = *(const float4*)&bq[o];
      s += w.x * v.x + w.y * v.y + w.z * v.z + w.w * v.w;
    }
    bqp[tid] = s;
  }
}

// ---- merged input prep: cvt in1 (2048 blk, grid-stride) + cvt_t in2 (4096
// ---- tile blocks: in2 f32 -> A2 bf16 + TX2 bf16 transpose)
__global__ __launch_bounds__(256) void k_in(
    const float* __restrict__ in1, const float* __restrict__ in2,
    u16* __restrict__ A1, u16* __restrict__ A2, u16* __restrict__ TX2) {
  __shared__ u16 t[64][36];
  const int b = blockIdx.x, tid = threadIdx.x;
  if (b < 2048) {
    const int n8 = 32768 * 512 / 8;
    for (int i = b * 256 + tid; i < n8; i += 2048 * 256) cvt8(in1, A1, i);
  } else {
    const int tb = b - 2048;                  // 4096 tiles: 4 x 64 x 16
    const int bx = (tb & 3) * 64;             // L base
    const int by = ((tb >> 2) & 63) * 32;     // key base
    const long z = tb >> 8;
    const float* s = in2 + z * (2048L * 256);
    u16* a = A2 + z * (2048L * 256);
    u16* d = TX2 + z * (256L * 2048);
    const int tx = tid & 31, ty = tid >> 5;   // (32,8)
#pragma unroll
    for (int i = 0; i < 4; i++) {
      const int row = by + ty + 8 * i;
      const float2 v = *(const float2*)&s[(size_t)row * 256 + bx + 2 * tx];
      const u16 e0 = f2bf(v.x), e1 = f2bf(v.y);
      *(unsigned*)&a[(size_t)row * 256 + bx + 2 * tx] =
          (unsigned)e0 | ((unsigned)e1 << 16);
      t[2 * tx][ty + 8 * i] = e0;
      t[2 * tx + 1][ty + 8 * i] = e1;
    }
    __syncthreads();
    const int col = tid >> 2, kc = (tid & 3) * 8;
    const u16* pr = &t[col][kc];
    int4 w;
    w.x = (int)((unsigned)pr[0] | ((unsigned)pr[1] << 16));
    w.y = (int)((unsigned)pr[2] | ((unsigned)pr[3] << 16));
    w.z = (int)((unsigned)pr[4] | ((unsigned)pr[5] << 16));
    w.w = (int)((unsigned)pr[6] | ((unsigned)pr[7] << 16));
    *(int4*)&d[(size_t)(bx + col) * 2048 + by + kc] = w;
  }
}

__device__ __forceinline__ void gl_lds16(const void* g, void* l) {
  __builtin_amdgcn_global_load_lds(
      (const __attribute__((address_space(1))) void*)g,
      (__attribute__((address_space(3))) void*)l, 16, 0, 0);
}

__device__ __forceinline__ void xcd_swz(int& bx, int& by, int& bz) {
  const int nx = gridDim.x, ny = gridDim.y, nz = gridDim.z;
  const long nwg = (long)nx * ny * nz;
  if (nwg & 7) return;
  long lin = (long)bx + (long)nx * ((long)by + (long)ny * bz);
  const long q = nwg >> 3;
  const long nl = (lin & 7) * q + (lin >> 3);
  bx = (int)(nl % nx);
  long r2 = nl / nx;
  by = (int)(r2 % ny);
  bz = (int)(r2 / ny);
}

#define MF(a, b, c) __builtin_amdgcn_mfma_f32_16x16x32_bf16(a, b, c, 0, 0, 0)

// ================== fused S~ / U kernel (QK || PV pipeline) ==================
// LDS: X2 dbuf 2x32K [0,64K) | TX2 dbuf 2x32K [64K,128K) | S dbuf 2x16K
// [128K,160K). part aliases S[0] (post-loop only). 160 KiB total, 1 block/CU.
__global__ __launch_bounds__(512, 2) void k_fused_su(
    const u16* __restrict__ Qp, const u16* __restrict__ X2g,
    const u16* __restrict__ TXg, u16* __restrict__ U,
    float* __restrict__ Iv, float scale) {
  __shared__ __align__(16) char lds[163840];
  float* part = (float*)(lds + 131072);  // aliases S[0]; used only post-loop

  int bxi = blockIdx.x, byi = blockIdx.y, bzi = blockIdx.z;
  xcd_swz(bxi, byi, bzi);
  const int tid = threadIdx.x, lane = tid & 63, wid = tid >> 6;
  const int fr = lane & 15, kq = lane >> 4, fr7 = fr & 7;
  const int row0 = bxi * 128;
  const long z = byi;
  const int kh = wid & 1, rq = wid >> 1;  // QK: 32 keys x 32 rows per wave
  const int wr = wid >> 2, wc = wid & 3;  // PV: 64 rows x 64 cols per wave

  bf16x8 qf[2][8];
  {
    const u16* qb = Qp + ((long)z * 2048 + row0 + rq * 32) * 256;
#pragma unroll
    for (int ni = 0; ni < 2; ni++)
#pragma unroll
      for (int kk = 0; kk < 8; kk++)
        qf[ni][kk] =
            *(const bf16x8*)(qb + (ni * 16 + fr) * 256 + kk * 32 + kq * 8);
  }

  const u16* gX2 = X2g + (long)z * (2048 * 256);
  const u16* gTX = TXg + (long)z * (256 * 2048);
  const int xrow = tid >> 5, xs = tid & 31;  // X2 tile: 64 rows x 512B
  const int trow = tid >> 3, ts = tid & 7;   // TX2 tile: 256 rows x 128B

#define STG_X2(ii, b) { \
  _Pragma("unroll") for (int p = 0; p < 4; p++) { \
    const int r_ = p * 16 + xrow; \
    gl_lds16(gX2 + ((long)(ii) * 64 + r_) * 256 + (xs ^ (r_ & 7)) * 8, \
             lds + (b) * 32768 + (p * 512 + tid) * 16); } }
#define STG_TX(ii, b) { \
  _Pragma("unroll") for (int p = 0; p < 4; p++) { \
    const int r_ = p * 64 + trow; \
    gl_lds16(gTX + (long)r_ * 2048 + (ii) * 64 + (ts ^ (r_ & 7)) * 8, \
             lds + 65536 + (b) * 32768 + (p * 512 + tid) * 16); } }

#define QK_BODY(xbuf, sbuf) { \
  f32x4 accS[2][2]; \
  accS[0][0] = zero; accS[0][1] = zero; accS[1][0] = zero; accS[1][1] = zero; \
  const char* xb = lds + (xbuf) * 32768; \
  _Pragma("unroll") for (int kk = 0; kk < 8; kk++) { \
    const int so = ((kk * 4 + kq) ^ fr7) << 4; \
    bf16x8 xf0 = *(const bf16x8*)(xb + (kh * 32 + fr) * 512 + so); \
    bf16x8 xf1 = *(const bf16x8*)(xb + (kh * 32 + 16 + fr) * 512 + so); \
    accS[0][0] = MF(xf0, qf[0][kk], accS[0][0]); \
    accS[0][1] = MF(xf0, qf[1][kk], accS[0][1]); \
    accS[1][0] = MF(xf1, qf[0][kk], accS[1][0]); \
    accS[1][1] = MF(xf1, qf[1][kk], accS[1][1]); \
  } \
  _Pragma("unroll") for (int mi = 0; mi < 2; mi++) \
  _Pragma("unroll") for (int ni = 0; ni < 2; ni++) { \
    u16 e[4]; float sum4 = 0.f; \
    _Pragma("unroll") for (int r = 0; r < 4; r++) { \
      float v = accS[mi][ni][r] * scale; \
      float ef = __expf(fminf(v, 30.f)); \
      e[r] = f2bf(ef); sum4 += bf2f(e[r]); \
    } \
    if (ni == 0) rs0 += sum4; else rs1 += sum4; \
    unsigned long long w = \
        (unsigned long long)((unsigned)e[0] | ((unsigned)e[1] << 16)) | \
        ((unsigned long long)((unsigned)e[2] | ((unsigned)e[3] << 16)) << 32); \
    const int row = rq * 32 + ni * 16 + fr; \
    const int inrow = (kh * 64 + mi * 32 + kq * 8) ^ (fr7 << 4); \
    *(unsigned long long*)(lds + 131072 + (sbuf) * 16384 + row * 128 + inrow) = w; \
  } }

#define PV_BODY(tbuf, sbuf) { \
  const char* tb = lds + 65536 + (tbuf) * 32768; \
  const char* sbase = lds + 131072 + (sbuf) * 16384; \
  _Pragma("unroll") for (int kk = 0; kk < 2; kk++) { \
    const int so = ((kk * 4 + kq) ^ fr7) << 4; \
    bf16x8 sf[4], tf[4]; \
    _Pragma("unroll") for (int m = 0; m < 4; m++) \
      sf[m] = *(const bf16x8*)(sbase + (wr * 64 + m * 16 + fr) * 128 + so); \
    _Pragma("unroll") for (int n = 0; n < 4; n++) \
      tf[n] = *(const bf16x8*)(tb + (wc * 64 + n * 16 + fr) * 128 + so); \
    _Pragma("unroll") for (int m = 0; m < 4; m++) \
    _Pragma("unroll") for (int n = 0; n < 4; n++) \
      accU[m][n] = MF(sf[m], tf[n], accU[m][n]); \
  } }

  f32x4 accU[4][4];
  const f32x4 zero = {0.f, 0.f, 0.f, 0.f};
#pragma unroll
  for (int m = 0; m < 4; m++)
#pragma unroll
    for (int n = 0; n < 4; n++) accU[m][n] = zero;
  float rs0 = 0.f, rs1 = 0.f;

  // prologue: X2(0), X2(1), TX2(0) = 12 ops in flight
  STG_X2(0, 0); STG_X2(1, 1); STG_TX(0, 0);
  asm volatile("s_waitcnt vmcnt(8)" ::: "memory");  // X2(0) landed
  __builtin_amdgcn_sched_barrier(0);
  __builtin_amdgcn_s_barrier();
  __builtin_amdgcn_s_setprio(1);
  QK_BODY(0, 0);
  __builtin_amdgcn_s_setprio(0);
  asm volatile("s_waitcnt lgkmcnt(0)" ::: "memory");
  __builtin_amdgcn_sched_barrier(0);
  __builtin_amdgcn_s_barrier();
  __builtin_amdgcn_sched_barrier(0);

  for (int i = 1; i < 32; i++) {
    const int cur = i & 1, prv = cur ^ 1;
    const int pre = (i + 1 > 31) ? 31 : i + 1;  // dup-stage keeps count uniform
    STG_X2(pre, (i + 1) & 1);                   // dup target is a dead buffer
    STG_TX(i, cur);
    asm volatile("s_waitcnt vmcnt(8)" ::: "memory");  // X2(i), TX2(i-1) landed
    __builtin_amdgcn_sched_barrier(0);
    __builtin_amdgcn_s_barrier();
    __builtin_amdgcn_sched_barrier(0);
    __builtin_amdgcn_s_setprio(1);
    QK_BODY(cur, cur);   // independent of PV below: compiler interleaves
    PV_BODY(prv, prv);
    __builtin_amdgcn_s_setprio(0);
    asm volatile("s_waitcnt lgkmcnt(0)" ::: "memory");
    __builtin_amdgcn_sched_barrier(0);
    __builtin_amdgcn_s_barrier();
    __builtin_amdgcn_sched_barrier(0);
  }

  asm volatile("s_waitcnt vmcnt(0)" ::: "memory");
  __builtin_amdgcn_sched_barrier(0);
  __builtin_amdgcn_s_barrier();
  __builtin_amdgcn_s_setprio(1);
  PV_BODY(1, 1);
  __builtin_amdgcn_s_setprio(0);

#undef STG_X2
#undef STG_TX
#undef QK_BODY
#undef PV_BODY

  // rowsums -> Iv (part aliases S[0]; S is dead now)
  __syncthreads();
  if (tid < 128) part[tid] = 0.f;
  __syncthreads();
  {
    float s0 = rs0, s1 = rs1;
    s0 += __shfl_xor(s0, 16); s0 += __shfl_xor(s0, 32);
    s1 += __shfl_xor(s1, 16); s1 += __shfl_xor(s1, 32);
    if (lane < 16) {
      atomicAdd(&part[rq * 32 + lane], s0);
      atomicAdd(&part[rq * 32 + 16 + lane], s1);
    }
  }
  __syncthreads();
  if (tid < 128) Iv[z * 2048 + row0 + tid] = 1.f / part[tid];

  // U store (unnormalized bf16; out-GEMM applies Iv)
  u16* ub = U + ((long)z * 2048 + row0) * 256;
#pragma unroll
  for (int m = 0; m < 4; m++)
#pragma unroll
    for (int n = 0; n < 4; n++) {
      const int col = wc * 64 + n * 16 + fr;
#pragma unroll
      for (int r = 0; r < 4; r++) {
        const int row = wr * 64 + m * 16 + kq * 4 + r;
        ub[row * 256 + col] = f2bf(accU[m][n][r]);
      }
    }
}

// =============== 256-row 8-wave gemm_bt (round-7 proven form) =================
#define SA(p, h, l, T) \
  gl_lds16(gA + (long)((h) * 128 + (l) * 64) * lda + (T) * 64, \
           dA + (p) * 32768 + (h) * 16384 + (l) * 8192)
#define SB(p, h, l, T) \
  gl_lds16(gB + (long)((h) * 128 + (l) * 64) * ldb + (T) * 64, \
           dB + (p) * (BNH * 16384) + (h) * 16384 + (l) * 8192)
#define RD_A(p, mh) { _Pragma("unroll") for (int m = 0; m < 4; m++) { \
    afr[m][0] = *(const bf16x8*)(lds + (p) * 32768 + aoffb + ((mh) * 64 + m * 16) * 128 + sb0); \
    afr[m][1] = *(const bf16x8*)(lds + (p) * 32768 + aoffb + ((mh) * 64 + m * 16) * 128 + sb1); } }
#define RD_B(p, nh, BF) { _Pragma("unroll") for (int n = 0; n < 2; n++) { \
    BF[n][0] = *(const bf16x8*)(lds + (p) * (BNH * 16384) + boffb + (((nh) * 2 + n) * 16) * 128 + sb0); \
    BF[n][1] = *(const bf16x8*)(lds + (p) * (BNH * 16384) + boffb + (((nh) * 2 + n) * 16) * 128 + sb1); } }
#define MFMA_QUAD(mh, nh, BF) { \
  _Pragma("unroll") for (int m = 0; m < 4; m++) \
  _Pragma("unroll") for (int n = 0; n < 2; n++) \
  _Pragma("unroll") for (int kk = 0; kk < 2; kk++) \
    acc[(mh) * 4 + m][(nh) * 2 + n] = MF(afr[m][kk], BF[n][kk], \
                                         acc[(mh) * 4 + m][(nh) * 2 + n]); }
#define BAR_MFMA_OPEN() \
  __builtin_amdgcn_sched_barrier(0); \
  __builtin_amdgcn_s_barrier(); \
  asm volatile("s_waitcnt lgkmcnt(0)" ::: "memory"); \
  __builtin_amdgcn_sched_barrier(0); \
  __builtin_amdgcn_s_setprio(1)
#define PH_CLOSE() \
  __builtin_amdgcn_s_setprio(0); \
  __builtin_amdgcn_sched_barrier(0); \
  __builtin_amdgcn_s_barrier(); \
  __builtin_amdgcn_sched_barrier(0)
#define PH_CLOSE_VM(N) \
  __builtin_amdgcn_s_setprio(0); \
  asm volatile("s_waitcnt vmcnt(" #N ")" ::: "memory"); \
  __builtin_amdgcn_sched_barrier(0); \
  __builtin_amdgcn_s_barrier(); \
  __builtin_amdgcn_sched_barrier(0)

template <int BNH, int OUT_BF16, int BIAS_MODE, int FUSE>
__global__ __launch_bounds__(512, 2) void k_gemm256(
    const u16* __restrict__ A, const u16* __restrict__ BT,
    void* __restrict__ Cv, const float* __restrict__ bias,
    const float* __restrict__ finv,
    int K, int lda, int ldb, int ldc, long sA, long sB, long sC, float scale) {
  __shared__ __align__(16) char lds[65536 + BNH * 32768 + 1024];
  float* part = (float*)(lds + 65536 + BNH * 32768);

  int bxi = blockIdx.x, byi = blockIdx.y, bzi = blockIdx.z;
  xcd_swz(bxi, byi, bzi);
  const int tid = threadIdx.x, lane = tid & 63, wid = tid >> 6;
  const int wr = wid >> 2, wc = wid & 3;
  const int fr = lane & 15, kq = lane >> 4, fr7 = fr & 7;
  const int brow = byi * 256, bcol = bxi * (BNH * 128);
  const long z = bzi;

  if (FUSE == 3 && tid < 256) part[tid] = finv[z * 2048 + brow + tid];

  const int srow = tid >> 3;
  const int sslot = (tid & 7) ^ (srow & 7);
  const u16* gA = A + z * sA + (long)(brow + srow) * lda + sslot * 8;
  const u16* gB = BT + z * sB + (long)(bcol + srow) * ldb + sslot * 8;
  char* dA = lds + tid * 16;
  char* dB = lds + 65536 + tid * 16;

  const int aoffb = (wr * 128 + fr) * 128;
  const int boffb = 65536 + (wc * (BNH * 32) + fr) * 128;
  const int sb0 = (kq ^ fr7) * 16;
  const int sb1 = ((4 + kq) ^ fr7) * 16;

  f32x4 acc[8][2 * BNH];
  const f32x4 zero = {0.f, 0.f, 0.f, 0.f};
#pragma unroll
  for (int m = 0; m < 8; m++)
#pragma unroll
    for (int n = 0; n < 2 * BNH; n++) acc[m][n] = zero;

  bf16x8 afr[4][2], bf0[2][2], bf1[2][2];
  const int iters = K >> 7;

  if (BNH == 2) {
    SA(0, 0, 0, 0); SA(0, 0, 1, 0); SA(0, 1, 0, 0); SA(0, 1, 1, 0);
    SB(0, 0, 0, 0); SB(0, 0, 1, 0); SB(0, 1, 0, 0); SB(0, 1, 1, 0);
    SB(1, 0, 0, 1); SB(1, 0, 1, 1); SB(1, 1, 0, 1); SB(1, 1, 1, 1);
    asm volatile("s_waitcnt vmcnt(4)" ::: "memory");
    __builtin_amdgcn_sched_barrier(0);
    __builtin_amdgcn_s_barrier();
    for (int i = 0; i < iters; i++) {
      const int t1 = 2 * i + 1, p0 = 2 * i + 2, p1 = 2 * i + 3;
      const bool more = (i + 1 < iters);
      RD_A(0, 0); RD_B(0, 0, bf0);
      SA(1, 0, 0, t1); SA(1, 0, 1, t1);
      BAR_MFMA_OPEN(); MFMA_QUAD(0, 0, bf0); PH_CLOSE();
      RD_B(0, 1, bf1);
      SA(1, 1, 0, t1); SA(1, 1, 1, t1);
      BAR_MFMA_OPEN(); MFMA_QUAD(0, 1, bf1); PH_CLOSE();
      RD_A(0, 1);
      if (more) { SB(0, 0, 0, p0); SB(0, 0, 1, p0); }
      BAR_MFMA_OPEN(); MFMA_QUAD(1, 0, bf0); PH_CLOSE();
      if (more) { SB(0, 1, 0, p0); SB(0, 1, 1, p0); }
      BAR_MFMA_OPEN(); MFMA_QUAD(1, 1, bf1);
      if (more) { PH_CLOSE_VM(4); } else { PH_CLOSE_VM(0); }
      RD_A(1, 0); RD_B(1, 0, bf0);
      if (more) { SA(0, 0, 0, p0); SA(0, 0, 1, p0); }
      BAR_MFMA_OPEN(); MFMA_QUAD(0, 0, bf0); PH_CLOSE();
      RD_B(1, 1, bf1);
      if (more) { SA(0, 1, 0, p0); SA(0, 1, 1, p0); }
      BAR_MFMA_OPEN(); MFMA_QUAD(0, 1, bf1); PH_CLOSE();
      RD_A(1, 1);
      if (more) { SB(1, 0, 0, p1); SB(1, 0, 1, p1); }
      BAR_MFMA_OPEN(); MFMA_QUAD(1, 0, bf0); PH_CLOSE();
      if (more) { SB(1, 1, 0, p1); SB(1, 1, 1, p1); }
      BAR_MFMA_OPEN(); MFMA_QUAD(1, 1, bf1);
      if (more) { PH_CLOSE_VM(4); } else { PH_CLOSE_VM(0); }
    }
  } else {
    SA(0, 0, 0, 0); SA(0, 0, 1, 0); SA(0, 1, 0, 0); SA(0, 1, 1, 0);
    SB(0, 0, 0, 0); SB(0, 0, 1, 0);
    SB(1, 0, 0, 1); SB(1, 0, 1, 1);
    asm volatile("s_waitcnt vmcnt(2)" ::: "memory");
    __builtin_amdgcn_sched_barrier(0);
    __builtin_amdgcn_s_barrier();
    for (int i = 0; i < iters; i++) {
      const int t1 = 2 * i + 1, p0 = 2 * i + 2, p1 = 2 * i + 3;
      const bool more = (i + 1 < iters);
      RD_A(0, 0); RD_B(0, 0, bf0);
      SA(1, 0, 0, t1); SA(1, 0, 1, t1);
      BAR_MFMA_OPEN(); MFMA_QUAD(0, 0, bf0); PH_CLOSE();
      RD_A(0, 1);
      SA(1, 1, 0, t1); SA(1, 1, 1, t1);
      if (more) { SB(0, 0, 0, p0); SB(0, 0, 1, p0); }
      BAR_MFMA_OPEN(); MFMA_QUAD(1, 0, bf0);
      if (more) { PH_CLOSE_VM(2); } else { PH_CLOSE_VM(0); }
      RD_A(1, 0); RD_B(1, 0, bf1);
      if (more) { SA(0, 0, 0, p0); SA(0, 0, 1, p0); }
      BAR_MFMA_OPEN(); MFMA_QUAD(0, 0, bf1); PH_CLOSE();
      RD_A(1, 1);
      if (more) { SA(0, 1, 0, p0); SA(0, 1, 1, p0);
                  SB(1, 0, 0, p1); SB(1, 0, 1, p1); }
      BAR_MFMA_OPEN(); MFMA_QUAD(1, 0, bf1);
      if (more) { PH_CLOSE_VM(2); } else { PH_CLOSE_VM(0); }
    }
  }

  const long zC = z * sC;
#pragma unroll
  for (int mi = 0; mi < 8; mi++) {
    const int r0 = brow + wr * 128 + mi * 16 + kq * 4;
#pragma unroll
    for (int n = 0; n < 2 * BNH; n++) {
      const int c = bcol + wc * (BNH * 32) + n * 16 + fr;
#pragma unroll
      for (int r = 0; r < 4; r++) {
        float v = acc[mi][n][r] * scale;
        if (BIAS_MODE == 1) v += bias[c];
        if (BIAS_MODE == 2) v += bias[r0 + r];
        if (FUSE == 3) v = v * part[r0 + r - brow] + bias[c];
        const long off = zC + (long)(r0 + r) * ldc + c;
        if (OUT_BF16) ((u16*)Cv)[off] = f2bf(v);
        else          ((float*)Cv)[off] = v;
      }
    }
  }
}

extern "C" void kernel_launch(void* const* d_in, const int* in_sizes, int n_in,
                              void* d_out, int out_size, void* d_ws, size_t ws_size,
                              hipStream_t stream) {
  (void)in_sizes; (void)n_in; (void)out_size;
  const float* in1 = (const float*)d_in[0];
  const float* in2 = (const float*)d_in[1];
  const float* Wq  = (const float*)d_in[2];
  const float* bq  = (const float*)d_in[3];
  const float* Wk  = (const float*)d_in[4];
  const float* Wv  = (const float*)d_in[6];
  const float* bv  = (const float*)d_in[7];
  float* out = (float*)d_out;

  const size_t MB = 1024ull * 1024ull;
  if (ws_size < 100 * MB) return;

  char* ws = (char*)d_ws;
  u16* A1   = (u16*)(ws + 0);                 // [32768][512] bf16 X1
  u16* A2   = (u16*)(ws + 32 * MB);           // [32768][256] bf16 X2
  u16* Qp   = (u16*)(ws + 48 * MB);           // [32768][256] Q'
  u16* TX2  = (u16*)(ws + 64 * MB);           // [16][256][2048] X2^T
  u16* U    = (u16*)(ws + 80 * MB);           // [32768][256] P~·X2
  u16* Wqb  = (u16*)(ws + 96 * MB);           // [512][512]
  u16* Wkb  = (u16*)(ws + 96 * MB + 524288);  // [256][512]
  u16* WvT  = (u16*)(ws + 96 * MB + 786432);  // [512][256]
  u16* WT1  = (u16*)(ws + 97 * MB);           // [256][512] Wk·Wq^T
  float* bqp = (float*)(ws + 97 * MB + 262144);   // [256]
  float* Iv  = (float*)(ws + 97 * MB + 524288);   // [32768] inv row sums

  // 1) merged weight prep + merged input prep
  k_prep<<<321, 256, 0, stream>>>(Wq, Wk, Wv, bq, Wqb, Wkb, WvT, bqp);
  k_in<<<6144, 256, 0, stream>>>(in1, in2, A1, A2, TX2);
  // 2) W' = Wk·Wq^T  (BNH=1: 4 blocks)
  k_gemm256<1, 1, 0, 0><<<dim3(4, 1, 1), 512, 0, stream>>>(
      Wkb, Wqb, WT1, nullptr, nullptr, 512, 512, 512, 512, 0, 0, 0, 1.f);
  // 3) Q' = X1·W'^T + bq'
  k_gemm256<1, 1, 1, 0><<<dim3(2, 128, 1), 512, 0, stream>>>(
      A1, WT1, Qp, bqp, nullptr, 512, 512, 512, 256, 0, 0, 0, 1.f);
  // 4) fused: S~ = exp(Q'·X2^T/sqrt(512)); U = S~·X2; Iv = 1/rowsum
  const float qk_scale = 0.044194173824159216f;
  k_fused_su<<<dim3(16, 16), 512, 0, stream>>>(Qp, A2, TX2, U, Iv, qk_scale);
  // 5) out = Iv·(U·WvT^T) + bv
  k_gemm256<2, 0, 0, 3><<<dim3(2, 128, 1), 512, 0, stream>>>(
      U, WvT, out, bv, Iv, 256, 256, 256, 512, 0, 0, 0, 1.f);
}

// Round 18
// 161.439 us; speedup vs baseline: 1.4709x; 1.0643x over previous
//
#include <hip/hip_runtime.h>

// CrossAttention B=16, N1=N2=2048, D=512, L=256 — algebraic restructure +
// fused S~/U kernel (QK(i) || PV(i-1) pipeline, counted vmcnt(8), S dbuf,
// 64-key geometry). Round 18 = round-17 + the in1->A1 round-trip deleted:
// k_qp reads in1 f32 directly and converts during reg-staged A staging
// (round-3 proven 128^2 2-phase structure); k_in now does in2 only.
//   W' = Wk·Wq^T, bq' = bq·Wk^T; Q' = X1·W'^T + bq'
//   fused: S = exp(Q'·X2^T/sqrt(512)) (LDS only), U = S·X2, Iv = 1/rowsum
//   out = Iv·(U·Wv) + bv

#define DIMD 512
#define LENL 256
#define BATCH 16
#define NQ 2048
#define NKV 2048

using bf16x8 = __attribute__((ext_vector_type(8))) __bf16;
using f32x4  = __attribute__((ext_vector_type(4))) float;
typedef unsigned short u16;

__device__ __forceinline__ u16 f2bf(float f) {
  union { float f; unsigned u; } x; x.f = f;
  return (u16)((x.u + 0x7fffu + ((x.u >> 16) & 1u)) >> 16);
}
__device__ __forceinline__ float bf2f(u16 b) {
  union { unsigned u; float f; } x; x.u = ((unsigned)b) << 16;
  return x.f;
}

__device__ __forceinline__ void cvt8(const float* __restrict__ src,
                                     u16* __restrict__ dst, int i) {
  float4 a = ((const float4*)src)[2 * i];
  float4 b = ((const float4*)src)[2 * i + 1];
  int4 o;
  o.x = (int)((unsigned)f2bf(a.x) | ((unsigned)f2bf(a.y) << 16));
  o.y = (int)((unsigned)f2bf(a.z) | ((unsigned)f2bf(a.w) << 16));
  o.z = (int)((unsigned)f2bf(b.x) | ((unsigned)f2bf(b.y) << 16));
  o.w = (int)((unsigned)f2bf(b.z) | ((unsigned)f2bf(b.w) << 16));
  ((int4*)dst)[i] = o;
}

// ---- merged weight prep: cvt Wq (128 blk), cvt Wk (64), transpose Wv (128),
// ---- bq' = bq·Wk^T (1)  => 321 blocks x 256 threads
__global__ __launch_bounds__(256) void k_prep(
    const float* __restrict__ Wq, const float* __restrict__ Wk,
    const float* __restrict__ Wv, const float* __restrict__ bq,
    u16* __restrict__ Wqb, u16* __restrict__ Wkb, u16* __restrict__ WvT,
    float* __restrict__ bqp) {
  __shared__ float t[32][33];
  const int b = blockIdx.x, tid = threadIdx.x;
  if (b < 128) {
    cvt8(Wq, Wqb, b * 256 + tid);
  } else if (b < 192) {
    cvt8(Wk, Wkb, (b - 128) * 256 + tid);
  } else if (b < 320) {
    const int tb = b - 192;
    const int bx = (tb & 15) * 32;   // N dir (512)
    const int by = (tb >> 4) * 32;   // K dir (256)
    const int tx = tid & 31, ty = tid >> 5;  // (32,8)
#pragma unroll
    for (int i = 0; i < 4; i++)
      t[ty + 8 * i][tx] = Wv[(size_t)(by + ty + 8 * i) * 512 + (bx + tx)];
    __syncthreads();
#pragma unroll
    for (int i = 0; i < 4; i++)
      WvT[(size_t)(bx + ty + 8 * i) * 256 + (by + tx)] =
          f2bf(t[tx][ty + 8 * i]);
  } else {
    float s = 0.f;
    for (int o = 0; o < 512; o += 4) {
      float4 w = *(const float4*)&Wk[(size_t)tid * 512 + o];
      float4 v = *(const float4*)&bq[o];
      s += w.x * v.x + w.y * v.y + w.z * v.z + w.w * v.w;
    }
    bqp[tid] = s;
  }
}

// ---- input prep: in2 f32 -> A2 bf16 + TX2 bf16 transpose (4096 tile blocks)
__global__ __launch_bounds__(256) void k_in(
    const float* __restrict__ in2, u16* __restrict__ A2,
    u16* __restrict__ TX2) {
  __shared__ u16 t[64][36];
  const int tb = blockIdx.x, tid = threadIdx.x;  // 4096 tiles: 4 x 64 x 16
  const int bx = (tb & 3) * 64;                  // L base
  const int by = ((tb >> 2) & 63) * 32;          // key base
  const long z = tb >> 8;
  const float* s = in2 + z * (2048L * 256);
  u16* a = A2 + z * (2048L * 256);
  u16* d = TX2 + z * (256L * 2048);
  const int tx = tid & 31, ty = tid >> 5;  // (32,8)
#pragma unroll
  for (int i = 0; i < 4; i++) {
    const int row = by + ty + 8 * i;
    const float2 v = *(const float2*)&s[(size_t)row * 256 + bx + 2 * tx];
    const u16 e0 = f2bf(v.x), e1 = f2bf(v.y);
    *(unsigned*)&a[(size_t)row * 256 + bx + 2 * tx] =
        (unsigned)e0 | ((unsigned)e1 << 16);
    t[2 * tx][ty + 8 * i] = e0;
    t[2 * tx + 1][ty + 8 * i] = e1;
  }
  __syncthreads();
  const int col = tid >> 2, kc = (tid & 3) * 8;
  const u16* pr = &t[col][kc];
  int4 w;
  w.x = (int)((unsigned)pr[0] | ((unsigned)pr[1] << 16));
  w.y = (int)((unsigned)pr[2] | ((unsigned)pr[3] << 16));
  w.z = (int)((unsigned)pr[4] | ((unsigned)pr[5] << 16));
  w.w = (int)((unsigned)pr[6] | ((unsigned)pr[7] << 16));
  *(int4*)&d[(size_t)(bx + col) * 2048 + by + kc] = w;
}

__device__ __forceinline__ void gl_lds16(const void* g, void* l) {
  __builtin_amdgcn_global_load_lds(
      (const __attribute__((address_space(1))) void*)g,
      (__attribute__((address_space(3))) void*)l, 16, 0, 0);
}

__device__ __forceinline__ void xcd_swz(int& bx, int& by, int& bz) {
  const int nx = gridDim.x, ny = gridDim.y, nz = gridDim.z;
  const long nwg = (long)nx * ny * nz;
  if (nwg & 7) return;
  long lin = (long)bx + (long)nx * ((long)by + (long)ny * bz);
  const long q = nwg >> 3;
  const long nl = (lin & 7) * q + (lin >> 3);
  bx = (int)(nl % nx);
  long r2 = nl / nx;
  by = (int)(r2 % ny);
  bz = (int)(r2 / ny);
}

#define MF(a, b, c) __builtin_amdgcn_mfma_f32_16x16x32_bf16(a, b, c, 0, 0, 0)

// ====== k_qp: Qp = in1(f32)·WT1^T + bq'  (128^2 tile, 2-phase, reg-staged A)
// Round-3 m97-style structure: 4 waves (2x2 of 64x64), BK=32, LDS dbuf.
// A staged from f32 via cvt + ds_write_b128 (bit-identical to cvt-then-load).
__global__ __launch_bounds__(256) void k_qp(
    const float* __restrict__ X1, const u16* __restrict__ WT1,
    u16* __restrict__ Qp, const float* __restrict__ bqp) {
  __shared__ __align__(16) u16 As[2][4096];  // [buf][128 rows x 32 bf16]
  __shared__ __align__(16) u16 Bs[2][4096];
  int bxi = blockIdx.x, byi = blockIdx.y, bzi = blockIdx.z;
  xcd_swz(bxi, byi, bzi);
  const int tid = threadIdx.x, lane = tid & 63, wid = tid >> 6;
  const int wr = wid >> 1, wc = wid & 1;
  const int brow = byi * 128, bcol = bxi * 128;

  const int srow = tid >> 2, scol = (tid & 3) * 8;
  const float* ga0 = X1 + (long)(brow + srow) * 512 + scol;
  const float* ga1 = ga0 + 64L * 512;
  const u16* gb0 = WT1 + (long)(bcol + srow) * 512 + scol;
  const u16* gb1 = gb0 + 64L * 512;

#define STA(k0, buf) { \
  float4 u0 = *(const float4*)(ga0 + (k0)); \
  float4 u1 = *(const float4*)(ga0 + (k0) + 4); \
  float4 v0 = *(const float4*)(ga1 + (k0)); \
  float4 v1 = *(const float4*)(ga1 + (k0) + 4); \
  int4 ou, ov; \
  ou.x = (int)((unsigned)f2bf(u0.x) | ((unsigned)f2bf(u0.y) << 16)); \
  ou.y = (int)((unsigned)f2bf(u0.z) | ((unsigned)f2bf(u0.w) << 16)); \
  ou.z = (int)((unsigned)f2bf(u1.x) | ((unsigned)f2bf(u1.y) << 16)); \
  ou.w = (int)((unsigned)f2bf(u1.z) | ((unsigned)f2bf(u1.w) << 16)); \
  ov.x = (int)((unsigned)f2bf(v0.x) | ((unsigned)f2bf(v0.y) << 16)); \
  ov.y = (int)((unsigned)f2bf(v0.z) | ((unsigned)f2bf(v0.w) << 16)); \
  ov.z = (int)((unsigned)f2bf(v1.x) | ((unsigned)f2bf(v1.y) << 16)); \
  ov.w = (int)((unsigned)f2bf(v1.z) | ((unsigned)f2bf(v1.w) << 16)); \
  *(int4*)((char*)As[buf] + tid * 16) = ou; \
  *(int4*)((char*)As[buf] + 4096 + tid * 16) = ov; }
#define STB(k0, buf) { \
  gl_lds16(gb0 + (k0), (char*)Bs[buf] + tid * 16); \
  gl_lds16(gb1 + (k0), (char*)Bs[buf] + 4096 + tid * 16); }

  f32x4 acc[4][4];
  const f32x4 zero = {0.f, 0.f, 0.f, 0.f};
#pragma unroll
  for (int m = 0; m < 4; m++)
#pragma unroll
    for (int n = 0; n < 4; n++) acc[m][n] = zero;

  const int kg = (lane >> 4) * 16;
  const int fr = lane & 15;

  STB(0, 0); STA(0, 0);
  __syncthreads();
  for (int t = 0; t < 16; t++) {
    const int cur = t & 1, nxt = cur ^ 1;
    if (t + 1 < 16) { STB((t + 1) * 32, nxt); STA((t + 1) * 32, nxt); }
    bf16x8 af[4], bfr[4];
#pragma unroll
    for (int m = 0; m < 4; m++)
      af[m] = *(const bf16x8*)((char*)As[cur] + (wr * 64 + m * 16 + fr) * 64 + kg);
#pragma unroll
    for (int n = 0; n < 4; n++)
      bfr[n] = *(const bf16x8*)((char*)Bs[cur] + (wc * 64 + n * 16 + fr) * 64 + kg);
#pragma unroll
    for (int m = 0; m < 4; m++)
#pragma unroll
      for (int n = 0; n < 4; n++)
        acc[m][n] = MF(af[m], bfr[n], acc[m][n]);
    __syncthreads();
  }
#undef STA
#undef STB

  // epilogue (m89 layout), bias[col], bf16 out, ldc=256
#pragma unroll
  for (int m = 0; m < 4; m++) {
    const int r0 = brow + wr * 64 + m * 16 + (lane >> 4) * 4;
#pragma unroll
    for (int n = 0; n < 4; n++) {
      const int c = bcol + wc * 64 + n * 16 + fr;
#pragma unroll
      for (int r = 0; r < 4; r++) {
        float v = acc[m][n][r] + bqp[c];
        Qp[(long)(r0 + r) * 256 + c] = f2bf(v);
      }
    }
  }
}

// ================== fused S~ / U kernel (QK || PV pipeline) ==================
// LDS: X2 dbuf 2x32K [0,64K) | TX2 dbuf 2x32K [64K,128K) | S dbuf 2x16K
// [128K,160K). part aliases S[0] (post-loop only). 160 KiB total, 1 block/CU.
__global__ __launch_bounds__(512, 2) void k_fused_su(
    const u16* __restrict__ Qp, const u16* __restrict__ X2g,
    const u16* __restrict__ TXg, u16* __restrict__ U,
    float* __restrict__ Iv, float scale) {
  __shared__ __align__(16) char lds[163840];
  float* part = (float*)(lds + 131072);  // aliases S[0]; used only post-loop

  int bxi = blockIdx.x, byi = blockIdx.y, bzi = blockIdx.z;
  xcd_swz(bxi, byi, bzi);
  const int tid = threadIdx.x, lane = tid & 63, wid = tid >> 6;
  const int fr = lane & 15, kq = lane >> 4, fr7 = fr & 7;
  const int row0 = bxi * 128;
  const long z = byi;
  const int kh = wid & 1, rq = wid >> 1;  // QK: 32 keys x 32 rows per wave
  const int wr = wid >> 2, wc = wid & 3;  // PV: 64 rows x 64 cols per wave

  bf16x8 qf[2][8];
  {
    const u16* qb = Qp + ((long)z * 2048 + row0 + rq * 32) * 256;
#pragma unroll
    for (int ni = 0; ni < 2; ni++)
#pragma unroll
      for (int kk = 0; kk < 8; kk++)
        qf[ni][kk] =
            *(const bf16x8*)(qb + (ni * 16 + fr) * 256 + kk * 32 + kq * 8);
  }

  const u16* gX2 = X2g + (long)z * (2048 * 256);
  const u16* gTX = TXg + (long)z * (256 * 2048);
  const int xrow = tid >> 5, xs = tid & 31;  // X2 tile: 64 rows x 512B
  const int trow = tid >> 3, ts = tid & 7;   // TX2 tile: 256 rows x 128B

#define STG_X2(ii, b) { \
  _Pragma("unroll") for (int p = 0; p < 4; p++) { \
    const int r_ = p * 16 + xrow; \
    gl_lds16(gX2 + ((long)(ii) * 64 + r_) * 256 + (xs ^ (r_ & 7)) * 8, \
             lds + (b) * 32768 + (p * 512 + tid) * 16); } }
#define STG_TX(ii, b) { \
  _Pragma("unroll") for (int p = 0; p < 4; p++) { \
    const int r_ = p * 64 + trow; \
    gl_lds16(gTX + (long)r_ * 2048 + (ii) * 64 + (ts ^ (r_ & 7)) * 8, \
             lds + 65536 + (b) * 32768 + (p * 512 + tid) * 16); } }

#define QK_BODY(xbuf, sbuf) { \
  f32x4 accS[2][2]; \
  accS[0][0] = zero; accS[0][1] = zero; accS[1][0] = zero; accS[1][1] = zero; \
  const char* xb = lds + (xbuf) * 32768; \
  _Pragma("unroll") for (int kk = 0; kk < 8; kk++) { \
    const int so = ((kk * 4 + kq) ^ fr7) << 4; \
    bf16x8 xf0 = *(const bf16x8*)(xb + (kh * 32 + fr) * 512 + so); \
    bf16x8 xf1 = *(const bf16x8*)(xb + (kh * 32 + 16 + fr) * 512 + so); \
    accS[0][0] = MF(xf0, qf[0][kk], accS[0][0]); \
    accS[0][1] = MF(xf0, qf[1][kk], accS[0][1]); \
    accS[1][0] = MF(xf1, qf[0][kk], accS[1][0]); \
    accS[1][1] = MF(xf1, qf[1][kk], accS[1][1]); \
  } \
  _Pragma("unroll") for (int mi = 0; mi < 2; mi++) \
  _Pragma("unroll") for (int ni = 0; ni < 2; ni++) { \
    u16 e[4]; float sum4 = 0.f; \
    _Pragma("unroll") for (int r = 0; r < 4; r++) { \
      float v = accS[mi][ni][r] * scale; \
      float ef = __expf(fminf(v, 30.f)); \
      e[r] = f2bf(ef); sum4 += bf2f(e[r]); \
    } \
    if (ni == 0) rs0 += sum4; else rs1 += sum4; \
    unsigned long long w = \
        (unsigned long long)((unsigned)e[0] | ((unsigned)e[1] << 16)) | \
        ((unsigned long long)((unsigned)e[2] | ((unsigned)e[3] << 16)) << 32); \
    const int row = rq * 32 + ni * 16 + fr; \
    const int inrow = (kh * 64 + mi * 32 + kq * 8) ^ (fr7 << 4); \
    *(unsigned long long*)(lds + 131072 + (sbuf) * 16384 + row * 128 + inrow) = w; \
  } }

#define PV_BODY(tbuf, sbuf) { \
  const char* tb = lds + 65536 + (tbuf) * 32768; \
  const char* sbase = lds + 131072 + (sbuf) * 16384; \
  _Pragma("unroll") for (int kk = 0; kk < 2; kk++) { \
    const int so = ((kk * 4 + kq) ^ fr7) << 4; \
    bf16x8 sf[4], tf[4]; \
    _Pragma("unroll") for (int m = 0; m < 4; m++) \
      sf[m] = *(const bf16x8*)(sbase + (wr * 64 + m * 16 + fr) * 128 + so); \
    _Pragma("unroll") for (int n = 0; n < 4; n++) \
      tf[n] = *(const bf16x8*)(tb + (wc * 64 + n * 16 + fr) * 128 + so); \
    _Pragma("unroll") for (int m = 0; m < 4; m++) \
    _Pragma("unroll") for (int n = 0; n < 4; n++) \
      accU[m][n] = MF(sf[m], tf[n], accU[m][n]); \
  } }

  f32x4 accU[4][4];
  const f32x4 zero = {0.f, 0.f, 0.f, 0.f};
#pragma unroll
  for (int m = 0; m < 4; m++)
#pragma unroll
    for (int n = 0; n < 4; n++) accU[m][n] = zero;
  float rs0 = 0.f, rs1 = 0.f;

  // prologue: X2(0), X2(1), TX2(0) = 12 ops in flight
  STG_X2(0, 0); STG_X2(1, 1); STG_TX(0, 0);
  asm volatile("s_waitcnt vmcnt(8)" ::: "memory");  // X2(0) landed
  __builtin_amdgcn_sched_barrier(0);
  __builtin_amdgcn_s_barrier();
  __builtin_amdgcn_s_setprio(1);
  QK_BODY(0, 0);
  __builtin_amdgcn_s_setprio(0);
  asm volatile("s_waitcnt lgkmcnt(0)" ::: "memory");
  __builtin_amdgcn_sched_barrier(0);
  __builtin_amdgcn_s_barrier();
  __builtin_amdgcn_sched_barrier(0);

  for (int i = 1; i < 32; i++) {
    const int cur = i & 1, prv = cur ^ 1;
    const int pre = (i + 1 > 31) ? 31 : i + 1;  // dup-stage keeps count uniform
    STG_X2(pre, (i + 1) & 1);                   // dup target is a dead buffer
    STG_TX(i, cur);
    asm volatile("s_waitcnt vmcnt(8)" ::: "memory");  // X2(i), TX2(i-1) landed
    __builtin_amdgcn_sched_barrier(0);
    __builtin_amdgcn_s_barrier();
    __builtin_amdgcn_sched_barrier(0);
    __builtin_amdgcn_s_setprio(1);
    QK_BODY(cur, cur);   // independent of PV below: compiler interleaves
    PV_BODY(prv, prv);
    __builtin_amdgcn_s_setprio(0);
    asm volatile("s_waitcnt lgkmcnt(0)" ::: "memory");
    __builtin_amdgcn_sched_barrier(0);
    __builtin_amdgcn_s_barrier();
    __builtin_amdgcn_sched_barrier(0);
  }

  asm volatile("s_waitcnt vmcnt(0)" ::: "memory");
  __builtin_amdgcn_sched_barrier(0);
  __builtin_amdgcn_s_barrier();
  __builtin_amdgcn_s_setprio(1);
  PV_BODY(1, 1);
  __builtin_amdgcn_s_setprio(0);

#undef STG_X2
#undef STG_TX
#undef QK_BODY
#undef PV_BODY

  // rowsums -> Iv (part aliases S[0]; S is dead now)
  __syncthreads();
  if (tid < 128) part[tid] = 0.f;
  __syncthreads();
  {
    float s0 = rs0, s1 = rs1;
    s0 += __shfl_xor(s0, 16); s0 += __shfl_xor(s0, 32);
    s1 += __shfl_xor(s1, 16); s1 += __shfl_xor(s1, 32);
    if (lane < 16) {
      atomicAdd(&part[rq * 32 + lane], s0);
      atomicAdd(&part[rq * 32 + 16 + lane], s1);
    }
  }
  __syncthreads();
  if (tid < 128) Iv[z * 2048 + row0 + tid] = 1.f / part[tid];

  // U store (unnormalized bf16; out-GEMM applies Iv)
  u16* ub = U + ((long)z * 2048 + row0) * 256;
#pragma unroll
  for (int m = 0; m < 4; m++)
#pragma unroll
    for (int n = 0; n < 4; n++) {
      const int col = wc * 64 + n * 16 + fr;
#pragma unroll
      for (int r = 0; r < 4; r++) {
        const int row = wr * 64 + m * 16 + kq * 4 + r;
        ub[row * 256 + col] = f2bf(accU[m][n][r]);
      }
    }
}

// =============== 256-row 8-wave gemm_bt (round-7 proven form) =================
#define SA(p, h, l, T) \
  gl_lds16(gA + (long)((h) * 128 + (l) * 64) * lda + (T) * 64, \
           dA + (p) * 32768 + (h) * 16384 + (l) * 8192)
#define SB(p, h, l, T) \
  gl_lds16(gB + (long)((h) * 128 + (l) * 64) * ldb + (T) * 64, \
           dB + (p) * (BNH * 16384) + (h) * 16384 + (l) * 8192)
#define RD_A(p, mh) { _Pragma("unroll") for (int m = 0; m < 4; m++) { \
    afr[m][0] = *(const bf16x8*)(lds + (p) * 32768 + aoffb + ((mh) * 64 + m * 16) * 128 + sb0); \
    afr[m][1] = *(const bf16x8*)(lds + (p) * 32768 + aoffb + ((mh) * 64 + m * 16) * 128 + sb1); } }
#define RD_B(p, nh, BF) { _Pragma("unroll") for (int n = 0; n < 2; n++) { \
    BF[n][0] = *(const bf16x8*)(lds + (p) * (BNH * 16384) + boffb + (((nh) * 2 + n) * 16) * 128 + sb0); \
    BF[n][1] = *(const bf16x8*)(lds + (p) * (BNH * 16384) + boffb + (((nh) * 2 + n) * 16) * 128 + sb1); } }
#define MFMA_QUAD(mh, nh, BF) { \
  _Pragma("unroll") for (int m = 0; m < 4; m++) \
  _Pragma("unroll") for (int n = 0; n < 2; n++) \
  _Pragma("unroll") for (int kk = 0; kk < 2; kk++) \
    acc[(mh) * 4 + m][(nh) * 2 + n] = MF(afr[m][kk], BF[n][kk], \
                                         acc[(mh) * 4 + m][(nh) * 2 + n]); }
#define BAR_MFMA_OPEN() \
  __builtin_amdgcn_sched_barrier(0); \
  __builtin_amdgcn_s_barrier(); \
  asm volatile("s_waitcnt lgkmcnt(0)" ::: "memory"); \
  __builtin_amdgcn_sched_barrier(0); \
  __builtin_amdgcn_s_setprio(1)
#define PH_CLOSE() \
  __builtin_amdgcn_s_setprio(0); \
  __builtin_amdgcn_sched_barrier(0); \
  __builtin_amdgcn_s_barrier(); \
  __builtin_amdgcn_sched_barrier(0)
#define PH_CLOSE_VM(N) \
  __builtin_amdgcn_s_setprio(0); \
  asm volatile("s_waitcnt vmcnt(" #N ")" ::: "memory"); \
  __builtin_amdgcn_sched_barrier(0); \
  __builtin_amdgcn_s_barrier(); \
  __builtin_amdgcn_sched_barrier(0)

template <int BNH, int OUT_BF16, int BIAS_MODE, int FUSE>
__global__ __launch_bounds__(512, 2) void k_gemm256(
    const u16* __restrict__ A, const u16* __restrict__ BT,
    void* __restrict__ Cv, const float* __restrict__ bias,
    const float* __restrict__ finv,
    int K, int lda, int ldb, int ldc, long sA, long sB, long sC, float scale) {
  __shared__ __align__(16) char lds[65536 + BNH * 32768 + 1024];
  float* part = (float*)(lds + 65536 + BNH * 32768);

  int bxi = blockIdx.x, byi = blockIdx.y, bzi = blockIdx.z;
  xcd_swz(bxi, byi, bzi);
  const int tid = threadIdx.x, lane = tid & 63, wid = tid >> 6;
  const int wr = wid >> 2, wc = wid & 3;
  const int fr = lane & 15, kq = lane >> 4, fr7 = fr & 7;
  const int brow = byi * 256, bcol = bxi * (BNH * 128);
  const long z = bzi;

  if (FUSE == 3 && tid < 256) part[tid] = finv[z * 2048 + brow + tid];

  const int srow = tid >> 3;
  const int sslot = (tid & 7) ^ (srow & 7);
  const u16* gA = A + z * sA + (long)(brow + srow) * lda + sslot * 8;
  const u16* gB = BT + z * sB + (long)(bcol + srow) * ldb + sslot * 8;
  char* dA = lds + tid * 16;
  char* dB = lds + 65536 + tid * 16;

  const int aoffb = (wr * 128 + fr) * 128;
  const int boffb = 65536 + (wc * (BNH * 32) + fr) * 128;
  const int sb0 = (kq ^ fr7) * 16;
  const int sb1 = ((4 + kq) ^ fr7) * 16;

  f32x4 acc[8][2 * BNH];
  const f32x4 zero = {0.f, 0.f, 0.f, 0.f};
#pragma unroll
  for (int m = 0; m < 8; m++)
#pragma unroll
    for (int n = 0; n < 2 * BNH; n++) acc[m][n] = zero;

  bf16x8 afr[4][2], bf0[2][2], bf1[2][2];
  const int iters = K >> 7;

  if (BNH == 2) {
    SA(0, 0, 0, 0); SA(0, 0, 1, 0); SA(0, 1, 0, 0); SA(0, 1, 1, 0);
    SB(0, 0, 0, 0); SB(0, 0, 1, 0); SB(0, 1, 0, 0); SB(0, 1, 1, 0);
    SB(1, 0, 0, 1); SB(1, 0, 1, 1); SB(1, 1, 0, 1); SB(1, 1, 1, 1);
    asm volatile("s_waitcnt vmcnt(4)" ::: "memory");
    __builtin_amdgcn_sched_barrier(0);
    __builtin_amdgcn_s_barrier();
    for (int i = 0; i < iters; i++) {
      const int t1 = 2 * i + 1, p0 = 2 * i + 2, p1 = 2 * i + 3;
      const bool more = (i + 1 < iters);
      RD_A(0, 0); RD_B(0, 0, bf0);
      SA(1, 0, 0, t1); SA(1, 0, 1, t1);
      BAR_MFMA_OPEN(); MFMA_QUAD(0, 0, bf0); PH_CLOSE();
      RD_B(0, 1, bf1);
      SA(1, 1, 0, t1); SA(1, 1, 1, t1);
      BAR_MFMA_OPEN(); MFMA_QUAD(0, 1, bf1); PH_CLOSE();
      RD_A(0, 1);
      if (more) { SB(0, 0, 0, p0); SB(0, 0, 1, p0); }
      BAR_MFMA_OPEN(); MFMA_QUAD(1, 0, bf0); PH_CLOSE();
      if (more) { SB(0, 1, 0, p0); SB(0, 1, 1, p0); }
      BAR_MFMA_OPEN(); MFMA_QUAD(1, 1, bf1);
      if (more) { PH_CLOSE_VM(4); } else { PH_CLOSE_VM(0); }
      RD_A(1, 0); RD_B(1, 0, bf0);
      if (more) { SA(0, 0, 0, p0); SA(0, 0, 1, p0); }
      BAR_MFMA_OPEN(); MFMA_QUAD(0, 0, bf0); PH_CLOSE();
      RD_B(1, 1, bf1);
      if (more) { SA(0, 1, 0, p0); SA(0, 1, 1, p0); }
      BAR_MFMA_OPEN(); MFMA_QUAD(0, 1, bf1); PH_CLOSE();
      RD_A(1, 1);
      if (more) { SB(1, 0, 0, p1); SB(1, 0, 1, p1); }
      BAR_MFMA_OPEN(); MFMA_QUAD(1, 0, bf0); PH_CLOSE();
      if (more) { SB(1, 1, 0, p1); SB(1, 1, 1, p1); }
      BAR_MFMA_OPEN(); MFMA_QUAD(1, 1, bf1);
      if (more) { PH_CLOSE_VM(4); } else { PH_CLOSE_VM(0); }
    }
  } else {
    SA(0, 0, 0, 0); SA(0, 0, 1, 0); SA(0, 1, 0, 0); SA(0, 1, 1, 0);
    SB(0, 0, 0, 0); SB(0, 0, 1, 0);
    SB(1, 0, 0, 1); SB(1, 0, 1, 1);
    asm volatile("s_waitcnt vmcnt(2)" ::: "memory");
    __builtin_amdgcn_sched_barrier(0);
    __builtin_amdgcn_s_barrier();
    for (int i = 0; i < iters; i++) {
      const int t1 = 2 * i + 1, p0 = 2 * i + 2, p1 = 2 * i + 3;
      const bool more = (i + 1 < iters);
      RD_A(0, 0); RD_B(0, 0, bf0);
      SA(1, 0, 0, t1); SA(1, 0, 1, t1);
      BAR_MFMA_OPEN(); MFMA_QUAD(0, 0, bf0); PH_CLOSE();
      RD_A(0, 1);
      SA(1, 1, 0, t1); SA(1, 1, 1, t1);
      if (more) { SB(0, 0, 0, p0); SB(0, 0, 1, p0); }
      BAR_MFMA_OPEN(); MFMA_QUAD(1, 0, bf0);
      if (more) { PH_CLOSE_VM(2); } else { PH_CLOSE_VM(0); }
      RD_A(1, 0); RD_B(1, 0, bf1);
      if (more) { SA(0, 0, 0, p0); SA(0, 0, 1, p0); }
      BAR_MFMA_OPEN(); MFMA_QUAD(0, 0, bf1); PH_CLOSE();
      RD_A(1, 1);
      if (more) { SA(0, 1, 0, p0); SA(0, 1, 1, p0);
                  SB(1, 0, 0, p1); SB(1, 0, 1, p1); }
      BAR_MFMA_OPEN(); MFMA_QUAD(1, 0, bf1);
      if (more) { PH_CLOSE_VM(2); } else { PH_CLOSE_VM(0); }
    }
  }

  const long zC = z * sC;
#pragma unroll
  for (int mi = 0; mi < 8; mi++) {
    const int r0 = brow + wr * 128 + mi * 16 + kq * 4;
#pragma unroll
    for (int n = 0; n < 2 * BNH; n++) {
      const int c = bcol + wc * (BNH * 32) + n * 16 + fr;
#pragma unroll
      for (int r = 0; r < 4; r++) {
        float v = acc[mi][n][r] * scale;
        if (BIAS_MODE == 1) v += bias[c];
        if (BIAS_MODE == 2) v += bias[r0 + r];
        if (FUSE == 3) v = v * part[r0 + r - brow] + bias[c];
        const long off = zC + (long)(r0 + r) * ldc + c;
        if (OUT_BF16) ((u16*)Cv)[off] = f2bf(v);
        else          ((float*)Cv)[off] = v;
      }
    }
  }
}

extern "C" void kernel_launch(void* const* d_in, const int* in_sizes, int n_in,
                              void* d_out, int out_size, void* d_ws, size_t ws_size,
                              hipStream_t stream) {
  (void)in_sizes; (void)n_in; (void)out_size;
  const float* in1 = (const float*)d_in[0];
  const float* in2 = (const float*)d_in[1];
  const float* Wq  = (const float*)d_in[2];
  const float* bq  = (const float*)d_in[3];
  const float* Wk  = (const float*)d_in[4];
  const float* Wv  = (const float*)d_in[6];
  const float* bv  = (const float*)d_in[7];
  float* out = (float*)d_out;

  const size_t MB = 1024ull * 1024ull;
  if (ws_size < 100 * MB) return;

  char* ws = (char*)d_ws;
  u16* A2   = (u16*)(ws + 32 * MB);           // [32768][256] bf16 X2
  u16* Qp   = (u16*)(ws + 48 * MB);           // [32768][256] Q'
  u16* TX2  = (u16*)(ws + 64 * MB);           // [16][256][2048] X2^T
  u16* U    = (u16*)(ws + 80 * MB);           // [32768][256] P~·X2
  u16* Wqb  = (u16*)(ws + 96 * MB);           // [512][512]
  u16* Wkb  = (u16*)(ws + 96 * MB + 524288);  // [256][512]
  u16* WvT  = (u16*)(ws + 96 * MB + 786432);  // [512][256]
  u16* WT1  = (u16*)(ws + 97 * MB);           // [256][512] Wk·Wq^T
  float* bqp = (float*)(ws + 97 * MB + 262144);   // [256]
  float* Iv  = (float*)(ws + 97 * MB + 524288);   // [32768] inv row sums

  // 1) weight prep + input prep (in2 only; in1 consumed directly by k_qp)
  k_prep<<<321, 256, 0, stream>>>(Wq, Wk, Wv, bq, Wqb, Wkb, WvT, bqp);
  k_in<<<4096, 256, 0, stream>>>(in2, A2, TX2);
  // 2) W' = Wk·Wq^T  (BNH=1: 4 blocks)
  k_gemm256<1, 1, 0, 0><<<dim3(4, 1, 1), 512, 0, stream>>>(
      Wkb, Wqb, WT1, nullptr, nullptr, 512, 512, 512, 512, 0, 0, 0, 1.f);
  // 3) Q' = in1(f32)·W'^T + bq'   (reg-staged cvt fused into staging)
  k_qp<<<dim3(2, 256, 1), 256, 0, stream>>>(in1, WT1, Qp, bqp);
  // 4) fused: S~ = exp(Q'·X2^T/sqrt(512)); U = S~·X2; Iv = 1/rowsum
  const float qk_scale = 0.044194173824159216f;
  k_fused_su<<<dim3(16, 16), 512, 0, stream>>>(Qp, A2, TX2, U, Iv, qk_scale);
  // 5) out = Iv·(U·WvT^T) + bv
  k_gemm256<2, 0, 0, 3><<<dim3(2, 128, 1), 512, 0, stream>>>(
      U, WvT, out, bv, Iv, 256, 256, 256, 512, 0, 0, 0, 1.f);
}